// Round 6
// baseline (663.725 us; speedup 1.0000x reference)
//
#include <hip/hip_runtime.h>
#include <math.h>

typedef unsigned short u16;
typedef __attribute__((ext_vector_type(8))) short bf16x8;
typedef __attribute__((ext_vector_type(4))) float f32x4;

// Problem constants (match reference)
constexpr int kF    = 32;    // nr_atom_basis
constexpr int kH    = 7;     // heads
constexpr int kC    = 224;   // F*H
constexpr int kRBF  = 50;
constexpr int kM    = 128;   // edge rows per MFMA pass
constexpr int kStr  = 232;   // LDS row stride (bf16; 464B, 16B-aligned, conflict-free)
constexpr int kG    = 4;     // nodes per fused block
constexpr float kCut = 5.0f;
constexpr float kEps = 1e-8f;

__device__ __forceinline__ float silu_f(float a) { return a / (1.f + __expf(-a)); }
__device__ __forceinline__ float tanh_f(float x) {
    x = fminf(fmaxf(x, -15.f), 15.f);
    float e = __expf(2.f * x);
    return (e - 1.f) / (e + 1.f);
}
__device__ __forceinline__ float bf2f(u16 u) {
    union { unsigned int i; float f; } v; v.i = ((unsigned int)u) << 16; return v.f;
}
__device__ __forceinline__ u16 f2bf(float f) {
    union { float f; unsigned int i; } v; v.f = f;
    unsigned int x = v.i;
    unsigned int round = ((x >> 16) & 1u) + 0x7fffu;
    return (u16)((x + round) >> 16);
}

// ---------------------------------------------------------------------------
// K0: zero histogram + cursors; build wxT (bf16, transposed w_xmix)
// ---------------------------------------------------------------------------
__global__ __launch_bounds__(256) void init_kernel(
    const float* __restrict__ wx, u16* __restrict__ wxT,
    int* __restrict__ counts, int* __restrict__ cursor, int N_)
{
    int idx = blockIdx.x * 256 + threadIdx.x;
    if (idx < kC * kC) {
        int c = idx / kC, k = idx - c * kC;      // wxT[c][k] = wx[k][c]
        wxT[idx] = f2bf(wx[k * kC + c]);
    }
    if (idx < N_) { counts[idx] = 0; cursor[idx] = 0; }
}

// ---------------------------------------------------------------------------
// K1: per-edge geometry + edge MLP + attention logits; histogram of idx_i
// ---------------------------------------------------------------------------
__global__ __launch_bounds__(256) void edge_kernel(
    const float* __restrict__ h, const float* __restrict__ x,
    const int* __restrict__ pl, int E_,
    const float* __restrict__ w_in, const float* __restrict__ b_in,
    const float* __restrict__ w_e1, const float* __restrict__ b_e1,
    const float* __restrict__ w_e2, const float* __restrict__ b_e2,
    const float* __restrict__ w_att, const float* __restrict__ b_att,
    float* __restrict__ he_g, float* __restrict__ logit_g,
    float* __restrict__ dir_g, int* __restrict__ counts)
{
    __shared__ float s_win[64 * kRBF];   // (2F, NRBF)
    __shared__ float s_we1[115 * kF];    // (2F+NRBF+1, F)
    __shared__ float s_we2[kF * kF];
    __shared__ float s_watt[kF * kH];
    __shared__ float s_bin[kRBF], s_be1[kF], s_be2[kF], s_batt[kH];

    int t = threadIdx.x;
    for (int idx = t; idx < 64 * kRBF; idx += 256) s_win[idx] = w_in[idx];
    for (int idx = t; idx < 115 * kF; idx += 256) s_we1[idx] = w_e1[idx];
    for (int idx = t; idx < kF * kF; idx += 256) s_we2[idx] = w_e2[idx];
    for (int idx = t; idx < kF * kH; idx += 256) s_watt[idx] = w_att[idx];
    if (t < kRBF) s_bin[t] = b_in[t];
    if (t < kF) { s_be1[t] = b_e1[t]; s_be2[t] = b_e2[t]; }
    if (t < kH) s_batt[t] = b_att[t];
    __syncthreads();

    int e = blockIdx.x * 256 + t;
    if (e >= E_) return;
    int i = pl[e], j = pl[E_ + e];

    float xi0 = x[i * 3 + 0], xi1 = x[i * 3 + 1], xi2 = x[i * 3 + 2];
    float r0 = x[j * 3 + 0] - xi0;
    float r1 = x[j * 3 + 1] - xi1;
    float r2 = x[j * 3 + 2] - xi2;
    float d = sqrtf(r0 * r0 + r1 * r1 + r2 * r2);
    float inv = 1.0f / (d + kEps);
    dir_g[(size_t)e * 3 + 0] = r0 * inv;
    dir_g[(size_t)e * 3 + 1] = r1 * inv;
    dir_g[(size_t)e * 3 + 2] = r2 * inv;

    const float* hi = h + (size_t)i * kF;
    const float* hj = h + (size_t)j * kF;

    // filt = rbf * (h_cat @ w_in + b_in)
    float facc[kRBF];
#pragma unroll
    for (int n = 0; n < kRBF; n++) facc[n] = 0.f;
    for (int f = 0; f < kF; f++) {
        float v = hi[f];
#pragma unroll
        for (int n = 0; n < kRBF; n++) facc[n] += v * s_win[f * kRBF + n];
    }
    for (int f = 0; f < kF; f++) {
        float v = hj[f];
#pragma unroll
        for (int n = 0; n < kRBF; n++) facc[n] += v * s_win[(kF + f) * kRBF + n];
    }
    const float invw = 49.0f / kCut;
    float dw = d * invw;
#pragma unroll
    for (int n = 0; n < kRBF; n++) {
        float a = dw - (float)n;
        facc[n] = __expf(-0.5f * a * a) * (facc[n] + s_bin[n]);
    }

    // t1 = silu(edge_in @ w_e1 + b_e1)
    float t1[kF];
#pragma unroll
    for (int o = 0; o < kF; o++) t1[o] = s_be1[o];
    for (int f = 0; f < kF; f++) {
        float v = hi[f];
#pragma unroll
        for (int o = 0; o < kF; o++) t1[o] += v * s_we1[f * kF + o];
    }
    for (int f = 0; f < kF; f++) {
        float v = hj[f];
#pragma unroll
        for (int o = 0; o < kF; o++) t1[o] += v * s_we1[(kF + f) * kF + o];
    }
#pragma unroll
    for (int n = 0; n < kRBF; n++) {
        float v = facc[n];
#pragma unroll
        for (int o = 0; o < kF; o++) t1[o] += v * s_we1[(64 + n) * kF + o];
    }
#pragma unroll
    for (int o = 0; o < kF; o++) t1[o] += d * s_we1[114 * kF + o];
#pragma unroll
    for (int o = 0; o < kF; o++) t1[o] = silu_f(t1[o]);

    // h_ij_edge = t1 @ w_e2 + b_e2
    float he[kF];
#pragma unroll
    for (int o = 0; o < kF; o++) he[o] = s_be2[o];
#pragma unroll
    for (int o = 0; o < kF; o++) {
        float v = t1[o];
#pragma unroll
        for (int o2 = 0; o2 < kF; o2++) he[o2] += v * s_we2[o * kF + o2];
    }
    float4* hp = (float4*)(he_g + (size_t)e * kF);
#pragma unroll
    for (int q = 0; q < 8; q++) {
        float4 v4;
        v4.x = he[4 * q + 0]; v4.y = he[4 * q + 1];
        v4.z = he[4 * q + 2]; v4.w = he[4 * q + 3];
        hp[q] = v4;
    }

    // att logits: celu(he @ w_att + b_att, alpha=2) * cutoff(d)
    float aw[kH];
#pragma unroll
    for (int hh = 0; hh < kH; hh++) aw[hh] = s_batt[hh];
#pragma unroll
    for (int f = 0; f < kF; f++) {
        float v = he[f];
#pragma unroll
        for (int hh = 0; hh < kH; hh++) aw[hh] += v * s_watt[f * kH + hh];
    }
    float cut = 0.f;
    if (d < kCut) cut = 0.5f * (__cosf(0.62831853071795864f * d) + 1.f);
#pragma unroll
    for (int hh = 0; hh < kH; hh++) {
        float a = aw[hh];
        a = (a >= 0.f) ? a : 2.f * (__expf(0.5f * a) - 1.f);
        logit_g[(size_t)e * kH + hh] = a * cut;
    }
    atomicAdd(&counts[i], 1);
}

// ---------------------------------------------------------------------------
// K2: exclusive scan, barrier-light (1 block, 1024 threads, ~20 barriers)
// ---------------------------------------------------------------------------
__global__ __launch_bounds__(1024) void scan_kernel(
    const int* __restrict__ counts, int* __restrict__ offsets, int n)
{
    __shared__ int buf[1024];
    int t = threadIdx.x;
    int chunk = (n + 1023) >> 10;
    int lo = t * chunk;
    int s = 0;
    for (int i = 0; i < chunk; i++) {
        int g = lo + i;
        if (g < n) s += counts[g];
    }
    buf[t] = s;
    __syncthreads();
    for (int off = 1; off < 1024; off <<= 1) {
        int v = (t >= off) ? buf[t - off] : 0;
        __syncthreads();
        buf[t] += v;
        __syncthreads();
    }
    int run = buf[t] - s;   // exclusive prefix of this thread's chunk
    for (int i = 0; i < chunk; i++) {
        int g = lo + i;
        if (g < n) { offsets[g] = run; run += counts[g]; }
    }
    if (t == 1023) offsets[n] = buf[1023];
}

// ---------------------------------------------------------------------------
// K3: scatter edges into CSR order
// ---------------------------------------------------------------------------
__global__ __launch_bounds__(256) void scatter_kernel(
    const int* __restrict__ pl, const int* __restrict__ offsets,
    int* __restrict__ cursor, int* __restrict__ sorted, int E_)
{
    int e = blockIdx.x * 256 + threadIdx.x;
    if (e < E_) {
        int i = pl[e];
        int p = atomicAdd(&cursor[i], 1);
        sorted[offsets[i] + p] = e;
    }
}

// ---------------------------------------------------------------------------
// K4: fused per-node-group kernel. Block b owns nodes [4b,4b+4) and their
// contiguous CSR edges. In-block: softmax stats, sem build (bf16), hisem
// walk, MFMA xmix + tanh, comb walk, cnsq/dv, node MLPs, outputs.
// Zero global atomics, zero intermediate global tensors.
// ---------------------------------------------------------------------------
__global__ __launch_bounds__(256) void fused_kernel(
    const float* __restrict__ h, const float* __restrict__ x, const float* __restrict__ v,
    const float* __restrict__ he_g, const float* __restrict__ logit_g,
    const float* __restrict__ dir_g,
    const int* __restrict__ offs, const int* __restrict__ sorted,
    const u16* __restrict__ wxT,
    const float* __restrict__ w_n1, const float* __restrict__ b_n1,
    const float* __restrict__ w_n2, const float* __restrict__ b_n2,
    const float* __restrict__ w_pn1, const float* __restrict__ b_pn1,
    const float* __restrict__ w_pn2, const float* __restrict__ b_pn2,
    const float* __restrict__ w_v1, const float* __restrict__ b_v1,
    const float* __restrict__ w_v2, const float* __restrict__ w_vmix,
    float* __restrict__ out_h, float* __restrict__ out_x, float* __restrict__ out_v,
    int N_)
{
    __shared__ __align__(16) u16 s_buf[kM][kStr];   // 59392 B: sem, then T
    __shared__ float s_att[kM][kH];                 // 3584
    __shared__ float s_dir[kM][3];                  // 1536
    __shared__ int   s_edid[kM];                    // 512
    __shared__ int   s_slot[kM];                    // 512
    __shared__ int   s_bnd[kG + 1];
    __shared__ float s_m[kG][kH], s_invs[kG][kH];
    __shared__ float s_cnsq[kG][kC];                // 3584
    __shared__ float s_hisem[kG][kC];               // 3584
    __shared__ float s_hn[kG][kF], s_sp1[kG][kF], s_spat[kG][kF], s_n1[kG][kF], s_g1[kG][kF];
    __shared__ float s_dv[kG][3];
    __shared__ float s_gate[kG];

    int t = threadIdx.x;
    int n0 = blockIdx.x * kG;
    if (t <= kG) s_bnd[t] = offs[min(n0 + t, N_)];
    if (t < kG * 3) ((float*)s_dv)[t] = 0.f;
    __syncthreads();
    int base_g = s_bnd[0];
    int cnt = s_bnd[kG] - base_g;

    // ---- per-node softmax stats: wave w owns node n0+w ----
    int w = t >> 6, lane = t & 63;
    {
        int nb_ = s_bnd[w];
        int deg = s_bnd[w + 1] - nb_;
        float m[kH], ss[kH];
#pragma unroll
        for (int hh = 0; hh < kH; hh++) { m[hh] = -1e30f; ss[hh] = 0.f; }
        for (int e = lane; e < deg; e += 64) {
            int ed = sorted[nb_ + e];
            const float* lp = logit_g + (size_t)ed * kH;
#pragma unroll
            for (int hh = 0; hh < kH; hh++) {
                float vv = lp[hh];
                if (vv > m[hh]) { ss[hh] *= __expf(m[hh] - vv); m[hh] = vv; }
                ss[hh] += __expf(vv - m[hh]);
            }
        }
#pragma unroll
        for (int hh = 0; hh < kH; hh++) {
            float mm = m[hh], s2 = ss[hh];
#pragma unroll
            for (int off = 32; off >= 1; off >>= 1) {
                float mo = __shfl_xor(mm, off);
                float so = __shfl_xor(s2, off);
                float mn = fmaxf(mm, mo);
                s2 = s2 * __expf(mm - mn) + so * __expf(mo - mn);
                mm = mn;
            }
            if (lane == 0) {
                s_m[w][hh] = mm;
                s_invs[w][hh] = (s2 > 0.f) ? 1.f / s2 : 0.f;
            }
        }
    }
    __syncthreads();

    // per-thread accumulators across passes (t<kC threads use them)
    float hs0 = 0.f, hs1 = 0.f, hs2 = 0.f, hs3 = 0.f;
    float cx0 = 0.f, cy0 = 0.f, cz0 = 0.f;
    float cx1 = 0.f, cy1 = 0.f, cz1 = 0.f;
    float cx2 = 0.f, cy2 = 0.f, cz2 = 0.f;
    float cx3 = 0.f, cy3 = 0.f, cz3 = 0.f;

    int quad = lane >> 4;
    int l15  = lane & 15;

    for (int p0 = 0; p0 < cnt; p0 += kM) {
        int cp = min(kM, cnt - p0);

        // stage edge ids + slots
        if (t < cp) {
            int gpos = base_g + p0 + t;
            s_edid[t] = sorted[gpos];
            s_slot[t] = (gpos >= s_bnd[1]) + (gpos >= s_bnd[2]) + (gpos >= s_bnd[3]);
        }
        __syncthreads();
        // dir + att
        for (int idx = t; idx < cp * 3; idx += 256) {
            int e = idx / 3, xx = idx - e * 3;
            s_dir[e][xx] = dir_g[(size_t)s_edid[e] * 3 + xx];
        }
        for (int idx = t; idx < cp * kH; idx += 256) {
            int e = idx / kH, hh = idx - e * kH;
            int sl = s_slot[e];
            s_att[e][hh] = __expf(logit_g[(size_t)s_edid[e] * kH + hh] - s_m[sl][hh])
                           * s_invs[sl][hh];
        }
        __syncthreads();
        // sem build: sem[e][f*7+hh] = he[e][f] * att[e][hh]  (bf16)
        for (int idx = t; idx < cp * kF; idx += 256) {
            int e = idx >> 5, f = idx & 31;
            float hv = he_g[(size_t)s_edid[e] * kF + f];
            u16 sw[7];
#pragma unroll
            for (int hh = 0; hh < kH; hh++) sw[hh] = f2bf(hv * s_att[e][hh]);
            u16* dst = &s_buf[e][f * 7];
            if ((f & 1) == 0) {
                *(unsigned int*)(dst)     = (unsigned int)sw[0] | ((unsigned int)sw[1] << 16);
                *(unsigned int*)(dst + 2) = (unsigned int)sw[2] | ((unsigned int)sw[3] << 16);
                *(unsigned int*)(dst + 4) = (unsigned int)sw[4] | ((unsigned int)sw[5] << 16);
                dst[6] = sw[6];
            } else {
                dst[0] = sw[0];
                *(unsigned int*)(dst + 1) = (unsigned int)sw[1] | ((unsigned int)sw[2] << 16);
                *(unsigned int*)(dst + 3) = (unsigned int)sw[3] | ((unsigned int)sw[4] << 16);
                *(unsigned int*)(dst + 5) = (unsigned int)sw[5] | ((unsigned int)sw[6] << 16);
            }
        }
        __syncthreads();

        // hisem walk (sem still in s_buf); slot branch is wave-uniform
        if (t < kC) {
            for (int e = 0; e < cp; e++) {
                float sv = bf2f(s_buf[e][t]);
                int sl = s_slot[e];
                if (sl == 0) hs0 += sv;
                else if (sl == 1) hs1 += sv;
                else if (sl == 2) hs2 += sv;
                else hs3 += sv;
            }
        }

        // A-fragments (own rows only)
        bool wactive = (32 * w < cp);
        bf16x8 afr[2][7];
        if (wactive) {
#pragma unroll
            for (int rt = 0; rt < 2; rt++)
#pragma unroll
                for (int kt = 0; kt < 7; kt++)
                    afr[rt][kt] = *(const bf16x8*)
                        &s_buf[32 * w + 16 * rt + l15][kt * 32 + quad * 8];
        }
        __syncthreads();   // hisem walk + A-loads done before T write-back

        if (wactive) {
            bf16x8 bA[7], bB[7];
            {
                const u16* bp = wxT + (size_t)l15 * kC + quad * 8;
#pragma unroll
                for (int kt = 0; kt < 7; kt++) bA[kt] = *(const bf16x8*)(bp + kt * 32);
            }
            for (int ct = 0; ct < 14; ct++) {
                bf16x8* cur = (ct & 1) ? bB : bA;
                bf16x8* nxt = (ct & 1) ? bA : bB;
                if (ct < 13) {
                    const u16* bp = wxT + (size_t)((ct + 1) * 16 + l15) * kC + quad * 8;
#pragma unroll
                    for (int kt = 0; kt < 7; kt++) nxt[kt] = *(const bf16x8*)(bp + kt * 32);
                }
                f32x4 acc0 = {0.f, 0.f, 0.f, 0.f};
                f32x4 acc1 = {0.f, 0.f, 0.f, 0.f};
#pragma unroll
                for (int kt = 0; kt < 7; kt++) {
                    acc0 = __builtin_amdgcn_mfma_f32_16x16x32_bf16(afr[0][kt], cur[kt], acc0, 0, 0, 0);
                    acc1 = __builtin_amdgcn_mfma_f32_16x16x32_bf16(afr[1][kt], cur[kt], acc1, 0, 0, 0);
                }
                int colg = ct * 16 + l15;
#pragma unroll
                for (int s = 0; s < 2; s++) {
                    f32x4 ac = s ? acc1 : acc0;
                    int rbase = 32 * w + 16 * s + quad * 4;
#pragma unroll
                    for (int r = 0; r < 4; r++)
                        s_buf[rbase + r][colg] = f2bf(tanh_f(ac[r]));
                }
            }
        }
        __syncthreads();

        // comb walk: T * dir accumulated per slot
        if (t < kC) {
            for (int e = 0; e < cp; e++) {
                float T = bf2f(s_buf[e][t]);
                float d0 = s_dir[e][0], d1 = s_dir[e][1], d2 = s_dir[e][2];
                int sl = s_slot[e];
                if (sl == 0)      { cx0 += T * d0; cy0 += T * d1; cz0 += T * d2; }
                else if (sl == 1) { cx1 += T * d0; cy1 += T * d1; cz1 += T * d2; }
                else if (sl == 2) { cx2 += T * d0; cy2 += T * d1; cz2 += T * d2; }
                else              { cx3 += T * d0; cy3 += T * d1; cz3 += T * d2; }
            }
        }
        __syncthreads();
    }

    // cnsq / hisem / dv finalize
    if (t < kC) {
        float wv = w_vmix[t];
        float i0 = 1.f / fmaxf((float)(s_bnd[1] - s_bnd[0]), 1.f);
        float i1 = 1.f / fmaxf((float)(s_bnd[2] - s_bnd[1]), 1.f);
        float i2 = 1.f / fmaxf((float)(s_bnd[3] - s_bnd[2]), 1.f);
        float i3 = 1.f / fmaxf((float)(s_bnd[4] - s_bnd[3]), 1.f);
        float m0, m1, m2;
        m0 = cx0 * i0; m1 = cy0 * i0; m2 = cz0 * i0;
        s_cnsq[0][t] = m0 * m0 + m1 * m1 + m2 * m2; s_hisem[0][t] = hs0;
        atomicAdd(&s_dv[0][0], wv * m0); atomicAdd(&s_dv[0][1], wv * m1); atomicAdd(&s_dv[0][2], wv * m2);
        m0 = cx1 * i1; m1 = cy1 * i1; m2 = cz1 * i1;
        s_cnsq[1][t] = m0 * m0 + m1 * m1 + m2 * m2; s_hisem[1][t] = hs1;
        atomicAdd(&s_dv[1][0], wv * m0); atomicAdd(&s_dv[1][1], wv * m1); atomicAdd(&s_dv[1][2], wv * m2);
        m0 = cx2 * i2; m1 = cy2 * i2; m2 = cz2 * i2;
        s_cnsq[2][t] = m0 * m0 + m1 * m1 + m2 * m2; s_hisem[2][t] = hs2;
        atomicAdd(&s_dv[2][0], wv * m0); atomicAdd(&s_dv[2][1], wv * m1); atomicAdd(&s_dv[2][2], wv * m2);
        m0 = cx3 * i3; m1 = cy3 * i3; m2 = cz3 * i3;
        s_cnsq[3][t] = m0 * m0 + m1 * m1 + m2 * m2; s_hisem[3][t] = hs3;
        atomicAdd(&s_dv[3][0], wv * m0); atomicAdd(&s_dv[3][1], wv * m1); atomicAdd(&s_dv[3][2], wv * m2);
    }
    __syncthreads();

    // ---- node MLPs: threads 0..127, slot = t>>5, ln = t&31 ----
    int slot = t >> 5, ln = t & 31;
    bool mval = (t < 128) && (n0 + slot < N_);
    int node = n0 + slot;
    if (mval) s_hn[slot][ln] = h[(size_t)node * kF + ln];
    __syncthreads();
    if (mval) {
        float a = b_pn1[ln];
        for (int c = 0; c < kC; c++) a += s_cnsq[slot][c] * w_pn1[c * kF + ln];
        s_sp1[slot][ln] = silu_f(a);
        float b = b_v1[ln];
        for (int f = 0; f < kF; f++) b += s_hn[slot][f] * w_v1[f * kF + ln];
        s_g1[slot][ln] = silu_f(b);
    }
    __syncthreads();
    if (mval) {
        float a = b_pn2[ln];
        for (int o = 0; o < kF; o++) a += s_sp1[slot][o] * w_pn2[o * kF + ln];
        s_spat[slot][ln] = silu_f(a);
        if (ln == 0) {
            float s = 0.f;
            for (int o = 0; o < kF; o++) s += s_g1[slot][o] * w_v2[o];
            s_gate[slot] = 2.f / (1.f + __expf(-s));
        }
    }
    __syncthreads();
    if (mval) {
        float a = b_n1[ln];
        for (int f = 0; f < kF; f++) a += s_hn[slot][f] * w_n1[f * kF + ln];
        for (int c = 0; c < kC; c++) a += s_hisem[slot][c] * w_n1[(kF + c) * kF + ln];
        for (int f = 0; f < kF; f++) a += s_spat[slot][f] * w_n1[(kF + kC + f) * kF + ln];
        s_n1[slot][ln] = silu_f(a);
    }
    __syncthreads();
    if (mval) {
        float a = b_n2[ln];
        for (int o = 0; o < kF; o++) a += s_n1[slot][o] * w_n2[o * kF + ln];
        out_h[(size_t)node * kF + ln] = s_hn[slot][ln] + silu_f(a);
        if (ln < 3) {
            float vv = v[(size_t)node * 3 + ln];
            float vu = s_gate[slot] * vv + s_dv[slot][ln];
            out_v[(size_t)node * 3 + ln] = vu;
            out_x[(size_t)node * 3 + ln] = x[(size_t)node * 3 + ln] + vu;
        }
    }
}

// ---------------------------------------------------------------------------
extern "C" void kernel_launch(void* const* d_in, const int* in_sizes, int n_in,
                              void* d_out, int out_size, void* d_ws, size_t ws_size,
                              hipStream_t stream)
{
    const float* h      = (const float*)d_in[0];
    const float* x      = (const float*)d_in[1];
    const float* v      = (const float*)d_in[2];
    const int*   pl     = (const int*)d_in[3];
    const float* w_in   = (const float*)d_in[4];
    const float* b_in   = (const float*)d_in[5];
    const float* w_e1   = (const float*)d_in[6];
    const float* b_e1   = (const float*)d_in[7];
    const float* w_e2   = (const float*)d_in[8];
    const float* b_e2   = (const float*)d_in[9];
    const float* w_att  = (const float*)d_in[10];
    const float* b_att  = (const float*)d_in[11];
    const float* w_n1   = (const float*)d_in[12];
    const float* b_n1   = (const float*)d_in[13];
    const float* w_n2   = (const float*)d_in[14];
    const float* b_n2   = (const float*)d_in[15];
    const float* w_pn1  = (const float*)d_in[16];
    const float* b_pn1  = (const float*)d_in[17];
    const float* w_pn2  = (const float*)d_in[18];
    const float* b_pn2  = (const float*)d_in[19];
    const float* w_v1   = (const float*)d_in[20];
    const float* b_v1   = (const float*)d_in[21];
    const float* w_v2   = (const float*)d_in[22];
    const float* w_xmix = (const float*)d_in[23];
    const float* w_vmix = (const float*)d_in[24];

    const int E_ = in_sizes[3] / 2;
    const int N_ = in_sizes[0] / kF;

    // Workspace (~34 MB; 16B-aligned segments first)
    char* w = (char*)d_ws;
    u16*   wxT     = (u16*)w;   w += (size_t)kC * kC * 2;
    float* he_g    = (float*)w; w += (size_t)E_ * kF * 4;
    float* logit_g = (float*)w; w += (size_t)E_ * kH * 4;
    float* dir_g   = (float*)w; w += (size_t)E_ * 3 * 4;
    int* counts    = (int*)w;   w += (size_t)N_ * 4;
    int* offs      = (int*)w;   w += (size_t)(N_ + 1) * 4;
    int* cursor    = (int*)w;   w += (size_t)N_ * 4;
    int* sorted    = (int*)w;   w += (size_t)E_ * 4;

    float* out_h = (float*)d_out;
    float* out_x = out_h + (size_t)N_ * kF;
    float* out_v = out_x + (size_t)N_ * 3;

    init_kernel<<<dim3((kC * kC + 255) / 256), dim3(256), 0, stream>>>(
        w_xmix, wxT, counts, cursor, N_);

    edge_kernel<<<dim3((E_ + 255) / 256), dim3(256), 0, stream>>>(
        h, x, pl, E_, w_in, b_in, w_e1, b_e1, w_e2, b_e2, w_att, b_att,
        he_g, logit_g, dir_g, counts);

    scan_kernel<<<dim3(1), dim3(1024), 0, stream>>>(counts, offs, N_);

    scatter_kernel<<<dim3((E_ + 255) / 256), dim3(256), 0, stream>>>(
        pl, offs, cursor, sorted, E_);

    fused_kernel<<<dim3((N_ + kG - 1) / kG), dim3(256), 0, stream>>>(
        h, x, v, he_g, logit_g, dir_g, offs, sorted, wxT,
        w_n1, b_n1, w_n2, b_n2, w_pn1, b_pn1, w_pn2, b_pn2,
        w_v1, b_v1, w_v2, w_vmix, out_h, out_x, out_v, N_);
}

// Round 7
// 509.336 us; speedup vs baseline: 1.3031x; 1.3031x over previous
//
#include <hip/hip_runtime.h>
#include <math.h>

typedef unsigned short u16;
typedef __attribute__((ext_vector_type(8))) short bf16x8;
typedef __attribute__((ext_vector_type(4))) float f32x4;

// Problem constants (match reference)
constexpr int kF    = 32;    // nr_atom_basis
constexpr int kH    = 7;     // heads
constexpr int kC    = 224;   // F*H
constexpr int kRBF  = 50;
constexpr int kM    = 128;   // edges per xmix block
constexpr int kStr  = 232;   // xmix LDS row stride (bf16; 464B, 16B-aligned)
constexpr int kCk   = 32;    // edge chunk in node kernel
constexpr float kCut = 5.0f;
constexpr float kEps = 1e-8f;

__device__ __forceinline__ float silu_f(float a) { return a / (1.f + __expf(-a)); }
__device__ __forceinline__ float tanh_f(float x) {
    x = fminf(fmaxf(x, -15.f), 15.f);
    float e = __expf(2.f * x);
    return (e - 1.f) / (e + 1.f);
}
__device__ __forceinline__ float bf2f(u16 u) {
    union { unsigned int i; float f; } v; v.i = ((unsigned int)u) << 16; return v.f;
}
__device__ __forceinline__ u16 f2bf(float f) {
    union { float f; unsigned int i; } v; v.f = f;
    unsigned int x = v.i;
    unsigned int round = ((x >> 16) & 1u) + 0x7fffu;
    return (u16)((x + round) >> 16);
}

// ---------------------------------------------------------------------------
// K0: zero histogram + cursors; build wxT (bf16, transposed w_xmix)
// ---------------------------------------------------------------------------
__global__ __launch_bounds__(256) void init_kernel(
    const float* __restrict__ wx, u16* __restrict__ wxT,
    int* __restrict__ counts, int* __restrict__ cursor, int N_)
{
    int idx = blockIdx.x * 256 + threadIdx.x;
    if (idx < kC * kC) {
        int c = idx / kC, k = idx - c * kC;      // wxT[c][k] = wx[k][c]
        wxT[idx] = f2bf(wx[k * kC + c]);
    }
    if (idx < N_) { counts[idx] = 0; cursor[idx] = 0; }
}

// ---------------------------------------------------------------------------
// K1: per-edge geometry + edge MLP + attention logits; histogram of idx_i.
// Weights read DIRECTLY from global: lane-uniform addresses -> scalar loads
// (SGPR operands fold free into v_fmac), avoiding the LDS-issue bottleneck.
// ---------------------------------------------------------------------------
__global__ __launch_bounds__(256) void edge_kernel(
    const float* __restrict__ h, const float* __restrict__ x,
    const int* __restrict__ pl, int E_,
    const float* __restrict__ w_in, const float* __restrict__ b_in,
    const float* __restrict__ w_e1, const float* __restrict__ b_e1,
    const float* __restrict__ w_e2, const float* __restrict__ b_e2,
    const float* __restrict__ w_att, const float* __restrict__ b_att,
    float* __restrict__ he_g, float* __restrict__ logit_g,
    float* __restrict__ dir_g, int* __restrict__ counts)
{
    int t = threadIdx.x;
    int e = blockIdx.x * 256 + t;
    if (e >= E_) return;
    int i = pl[e], j = pl[E_ + e];

    float xi0 = x[i * 3 + 0], xi1 = x[i * 3 + 1], xi2 = x[i * 3 + 2];
    float r0 = x[j * 3 + 0] - xi0;
    float r1 = x[j * 3 + 1] - xi1;
    float r2 = x[j * 3 + 2] - xi2;
    float d = sqrtf(r0 * r0 + r1 * r1 + r2 * r2);
    float inv = 1.0f / (d + kEps);
    dir_g[(size_t)e * 3 + 0] = r0 * inv;
    dir_g[(size_t)e * 3 + 1] = r1 * inv;
    dir_g[(size_t)e * 3 + 2] = r2 * inv;

    // gather h_i, h_j into registers (vectorized)
    float hi[kF], hj[kF];
    {
        const float4* pi = (const float4*)(h + (size_t)i * kF);
        const float4* pj = (const float4*)(h + (size_t)j * kF);
#pragma unroll
        for (int q = 0; q < 8; q++) {
            float4 a = pi[q], b = pj[q];
            hi[4 * q + 0] = a.x; hi[4 * q + 1] = a.y; hi[4 * q + 2] = a.z; hi[4 * q + 3] = a.w;
            hj[4 * q + 0] = b.x; hj[4 * q + 1] = b.y; hj[4 * q + 2] = b.z; hj[4 * q + 3] = b.w;
        }
    }

    // filt = rbf * (h_cat @ w_in + b_in)
    float facc[kRBF];
#pragma unroll
    for (int n = 0; n < kRBF; n++) facc[n] = 0.f;
    for (int f = 0; f < kF; f++) {
        float v = hi[f];
#pragma unroll
        for (int n = 0; n < kRBF; n++) facc[n] += v * w_in[f * kRBF + n];
    }
    for (int f = 0; f < kF; f++) {
        float v = hj[f];
#pragma unroll
        for (int n = 0; n < kRBF; n++) facc[n] += v * w_in[(kF + f) * kRBF + n];
    }
    const float invw = 49.0f / kCut;
    float dw = d * invw;
#pragma unroll
    for (int n = 0; n < kRBF; n++) {
        float a = dw - (float)n;
        facc[n] = __expf(-0.5f * a * a) * (facc[n] + b_in[n]);
    }

    // t1 = silu(edge_in @ w_e1 + b_e1)
    float t1[kF];
#pragma unroll
    for (int o = 0; o < kF; o++) t1[o] = b_e1[o];
    for (int f = 0; f < kF; f++) {
        float v = hi[f];
#pragma unroll
        for (int o = 0; o < kF; o++) t1[o] += v * w_e1[f * kF + o];
    }
    for (int f = 0; f < kF; f++) {
        float v = hj[f];
#pragma unroll
        for (int o = 0; o < kF; o++) t1[o] += v * w_e1[(kF + f) * kF + o];
    }
#pragma unroll
    for (int n = 0; n < kRBF; n++) {
        float v = facc[n];
#pragma unroll
        for (int o = 0; o < kF; o++) t1[o] += v * w_e1[(64 + n) * kF + o];
    }
#pragma unroll
    for (int o = 0; o < kF; o++) t1[o] += d * w_e1[114 * kF + o];
#pragma unroll
    for (int o = 0; o < kF; o++) t1[o] = silu_f(t1[o]);

    // h_ij_edge = t1 @ w_e2 + b_e2
    float he[kF];
#pragma unroll
    for (int o = 0; o < kF; o++) he[o] = b_e2[o];
#pragma unroll
    for (int o = 0; o < kF; o++) {
        float v = t1[o];
#pragma unroll
        for (int o2 = 0; o2 < kF; o2++) he[o2] += v * w_e2[o * kF + o2];
    }
    float4* hp = (float4*)(he_g + (size_t)e * kF);
#pragma unroll
    for (int q = 0; q < 8; q++) {
        float4 v4;
        v4.x = he[4 * q + 0]; v4.y = he[4 * q + 1];
        v4.z = he[4 * q + 2]; v4.w = he[4 * q + 3];
        hp[q] = v4;
    }

    // att logits: celu(he @ w_att + b_att, alpha=2) * cutoff(d)
    float aw[kH];
#pragma unroll
    for (int hh = 0; hh < kH; hh++) aw[hh] = b_att[hh];
#pragma unroll
    for (int f = 0; f < kF; f++) {
        float v = he[f];
#pragma unroll
        for (int hh = 0; hh < kH; hh++) aw[hh] += v * w_att[f * kH + hh];
    }
    float cut = 0.f;
    if (d < kCut) cut = 0.5f * (__cosf(0.62831853071795864f * d) + 1.f);
#pragma unroll
    for (int hh = 0; hh < kH; hh++) {
        float a = aw[hh];
        a = (a >= 0.f) ? a : 2.f * (__expf(0.5f * a) - 1.f);
        logit_g[(size_t)e * kH + hh] = a * cut;
    }
    atomicAdd(&counts[i], 1);
}

// ---------------------------------------------------------------------------
// K2: exclusive scan, barrier-light (1 block, 1024 threads)
// ---------------------------------------------------------------------------
__global__ __launch_bounds__(1024) void scan_kernel(
    const int* __restrict__ counts, int* __restrict__ offsets, int n)
{
    __shared__ int buf[1024];
    int t = threadIdx.x;
    int chunk = (n + 1023) >> 10;
    int lo = t * chunk;
    int s = 0;
    for (int i = 0; i < chunk; i++) {
        int g = lo + i;
        if (g < n) s += counts[g];
    }
    buf[t] = s;
    __syncthreads();
    for (int off = 1; off < 1024; off <<= 1) {
        int v = (t >= off) ? buf[t - off] : 0;
        __syncthreads();
        buf[t] += v;
        __syncthreads();
    }
    int run = buf[t] - s;
    for (int i = 0; i < chunk; i++) {
        int g = lo + i;
        if (g < n) { offsets[g] = run; run += counts[g]; }
    }
    if (t == 1023) offsets[n] = buf[1023];
}

// ---------------------------------------------------------------------------
// K3: scatter edges into CSR order
// ---------------------------------------------------------------------------
__global__ __launch_bounds__(256) void scatter_kernel(
    const int* __restrict__ pl, const int* __restrict__ offsets,
    int* __restrict__ cursor, int* __restrict__ sorted, int E_)
{
    int e = blockIdx.x * 256 + threadIdx.x;
    if (e < E_) {
        int i = pl[e];
        int p = atomicAdd(&cursor[i], 1);
        sorted[offsets[i] + p] = e;
    }
}

// ---------------------------------------------------------------------------
// K4: per-node softmax stats (wave per node, all 7 heads per edge pass)
// ---------------------------------------------------------------------------
__global__ __launch_bounds__(256) void stats_kernel(
    const float* __restrict__ logit_g, const int* __restrict__ offsets,
    const int* __restrict__ sorted,
    float* __restrict__ m_g, float* __restrict__ invs_g, int N_)
{
    int wave = threadIdx.x >> 6;
    int lane = threadIdx.x & 63;
    int node = blockIdx.x * 4 + wave;
    if (node >= N_) return;
    int base = offsets[node];
    int deg  = offsets[node + 1] - base;

    float m[kH], ss[kH];
#pragma unroll
    for (int hh = 0; hh < kH; hh++) { m[hh] = -1e30f; ss[hh] = 0.f; }
    for (int e = lane; e < deg; e += 64) {
        int ed = sorted[base + e];
        const float* lp = logit_g + (size_t)ed * kH;
#pragma unroll
        for (int hh = 0; hh < kH; hh++) {
            float vv = lp[hh];
            if (vv > m[hh]) { ss[hh] *= __expf(m[hh] - vv); m[hh] = vv; }
            ss[hh] += __expf(vv - m[hh]);
        }
    }
#pragma unroll
    for (int hh = 0; hh < kH; hh++) {
        float mm = m[hh], s2 = ss[hh];
#pragma unroll
        for (int off = 32; off >= 1; off >>= 1) {
            float mo = __shfl_xor(mm, off);
            float so = __shfl_xor(s2, off);
            float mn = fmaxf(mm, mo);
            s2 = s2 * __expf(mm - mn) + so * __expf(mo - mn);
            mm = mn;
        }
        if (lane == 0) {
            m_g[(size_t)node * kH + hh] = mm;
            invs_g[(size_t)node * kH + hh] = (s2 > 0.f) ? 1.f / s2 : 0.f;
        }
    }
}

// ---------------------------------------------------------------------------
// K5: MFMA xmix kernel (r5-proven). T[pos][c] = tanh(sem @ wx), bf16, CSR order
// ---------------------------------------------------------------------------
__global__ __launch_bounds__(256) void xmix_kernel(
    const float* __restrict__ he_g, const float* __restrict__ logit_g,
    const int* __restrict__ pl, const int* __restrict__ sorted,
    const float* __restrict__ m_g, const float* __restrict__ invs_g,
    const u16* __restrict__ wxT, int E_, u16* __restrict__ T_g)
{
    __shared__ __align__(16) u16 s_buf[kM][kStr];
    __shared__ float s_att[kM][kH];
    __shared__ int   s_ed[kM];

    int t = threadIdx.x;
    int T0 = blockIdx.x * kM;

    if (t < kM) {
        int gi = T0 + t;
        s_ed[t] = (gi < E_) ? sorted[gi] : -1;
    }
    __syncthreads();

    for (int idx = t; idx < kM * kH; idx += 256) {
        int e = idx / kH, hh = idx - e * kH;
        int ed = s_ed[e];
        float a = 0.f;
        if (ed >= 0) {
            int nd = pl[ed];
            a = __expf(logit_g[(size_t)ed * kH + hh] - m_g[(size_t)nd * kH + hh])
                * invs_g[(size_t)nd * kH + hh];
        }
        s_att[e][hh] = a;
    }
    __syncthreads();

#pragma unroll
    for (int p = 0; p < kM * kF / 256; p++) {
        int idx = t + 256 * p;
        int e = idx >> 5, f = idx & 31;
        int ed = s_ed[e];
        float hv = (ed >= 0) ? he_g[(size_t)ed * kF + f] : 0.f;
        u16 sw[7];
#pragma unroll
        for (int hh = 0; hh < kH; hh++) sw[hh] = f2bf(hv * s_att[e][hh]);
        u16* dst = &s_buf[e][f * 7];
        if ((f & 1) == 0) {
            *(unsigned int*)(dst)     = (unsigned int)sw[0] | ((unsigned int)sw[1] << 16);
            *(unsigned int*)(dst + 2) = (unsigned int)sw[2] | ((unsigned int)sw[3] << 16);
            *(unsigned int*)(dst + 4) = (unsigned int)sw[4] | ((unsigned int)sw[5] << 16);
            dst[6] = sw[6];
        } else {
            dst[0] = sw[0];
            *(unsigned int*)(dst + 1) = (unsigned int)sw[1] | ((unsigned int)sw[2] << 16);
            *(unsigned int*)(dst + 3) = (unsigned int)sw[3] | ((unsigned int)sw[4] << 16);
            *(unsigned int*)(dst + 5) = (unsigned int)sw[5] | ((unsigned int)sw[6] << 16);
        }
    }
    __syncthreads();

    int w    = t >> 6;
    int lane = t & 63;
    int quad = lane >> 4;
    int l15  = lane & 15;

    bf16x8 afr[2][7];
#pragma unroll
    for (int rt = 0; rt < 2; rt++)
#pragma unroll
        for (int kt = 0; kt < 7; kt++)
            afr[rt][kt] = *(const bf16x8*)&s_buf[32 * w + 16 * rt + l15][kt * 32 + quad * 8];

    bf16x8 bA[7], bB[7];
    {
        const u16* bp = wxT + (size_t)l15 * kC + quad * 8;
#pragma unroll
        for (int kt = 0; kt < 7; kt++) bA[kt] = *(const bf16x8*)(bp + kt * 32);
    }
    __syncthreads();

    for (int ct = 0; ct < 14; ct++) {
        bf16x8* cur = (ct & 1) ? bB : bA;
        bf16x8* nxt = (ct & 1) ? bA : bB;
        if (ct < 13) {
            const u16* bp = wxT + (size_t)((ct + 1) * 16 + l15) * kC + quad * 8;
#pragma unroll
            for (int kt = 0; kt < 7; kt++) nxt[kt] = *(const bf16x8*)(bp + kt * 32);
        }
        f32x4 acc0 = {0.f, 0.f, 0.f, 0.f};
        f32x4 acc1 = {0.f, 0.f, 0.f, 0.f};
#pragma unroll
        for (int kt = 0; kt < 7; kt++) {
            acc0 = __builtin_amdgcn_mfma_f32_16x16x32_bf16(afr[0][kt], cur[kt], acc0, 0, 0, 0);
            acc1 = __builtin_amdgcn_mfma_f32_16x16x32_bf16(afr[1][kt], cur[kt], acc1, 0, 0, 0);
        }
        int colg = ct * 16 + l15;
#pragma unroll
        for (int s = 0; s < 2; s++) {
            f32x4 ac = s ? acc1 : acc0;
            int rbase = 32 * w + 16 * s + quad * 4;
#pragma unroll
            for (int r = 0; r < 4; r++)
                s_buf[rbase + r][colg] = f2bf(tanh_f(ac[r]));
        }
    }
    __syncthreads();

#pragma unroll
    for (int it = 0; it < 14; it++) {
        int idx = t + 256 * it;
        int row = idx / 28, ch = idx - row * 28;
        uint4 vv = *(const uint4*)&s_buf[row][ch * 8];
        *(uint4*)(T_g + ((size_t)(T0 + row) * kC + ch * 8)) = vv;
    }
}

// ---------------------------------------------------------------------------
// K6: one block per node — comb/hisem from T rows (transposed conflict-free
// LDS), then node MLPs parallelized over all 256 threads.
// ---------------------------------------------------------------------------
__global__ __launch_bounds__(256) void node_kernel(
    const float* __restrict__ h, const float* __restrict__ x, const float* __restrict__ v,
    const u16* __restrict__ T_g, const float* __restrict__ he_g,
    const float* __restrict__ logit_g, const float* __restrict__ dir_g,
    const int* __restrict__ offsets, const int* __restrict__ sorted,
    const float* __restrict__ m_g, const float* __restrict__ invs_g,
    const float* __restrict__ w_n1, const float* __restrict__ b_n1,
    const float* __restrict__ w_n2, const float* __restrict__ b_n2,
    const float* __restrict__ w_pn1, const float* __restrict__ b_pn1,
    const float* __restrict__ w_pn2, const float* __restrict__ b_pn2,
    const float* __restrict__ w_v1, const float* __restrict__ b_v1,
    const float* __restrict__ w_v2, const float* __restrict__ w_vmix,
    float* __restrict__ out_h, float* __restrict__ out_x, float* __restrict__ out_v,
    int N_)
{
    __shared__ float s_Tt[kC][kCk + 1];   // transposed: (c*33+el)%32 spans banks
    __shared__ float s_he[kCk][kF];
    __shared__ float s_att[kCk][kH];
    __shared__ float s_dir[kCk][3];
    __shared__ int   s_ed[kCk];
    __shared__ float s_cm[3][kC];
    __shared__ float s_cnsq[kC];
    __shared__ float s_hisem[kC];
    __shared__ float s_part[8][kF];
    __shared__ float s_pdv[3][32];
    __shared__ float s_ni[kF + kC + kF];  // 288
    __shared__ float s_hn[kF], s_sp1[kF], s_spat[kF], s_n1[kF], s_g1[kF];
    __shared__ float s_gate, s_dv[3];

    int node = blockIdx.x;
    int t = threadIdx.x;
    int base = offsets[node];
    int deg  = offsets[node + 1] - base;

    float c0 = 0.f, c1 = 0.f, c2 = 0.f, hs = 0.f;
    int f7 = t / kH, h7 = t - f7 * kH;    // valid for t<kC

    for (int e0 = 0; e0 < deg; e0 += kCk) {
        int ce = min(kCk, deg - e0);
        if (t < ce) s_ed[t] = sorted[base + e0 + t];
        __syncthreads();
        // stage T rows transposed into fp32 LDS
        for (int idx = t; idx < ce * 28; idx += 256) {
            int el = idx / 28, ch = idx - el * 28;
            uint4 vv = *(const uint4*)(T_g + ((size_t)(base + e0 + el) * kC + ch * 8));
            const u16* pv = (const u16*)&vv;
            int cb = ch * 8;
#pragma unroll
            for (int q = 0; q < 8; q++) s_Tt[cb + q][el] = bf2f(pv[q]);
        }
        for (int idx = t; idx < ce * 8; idx += 256) {
            int el = idx >> 3, q = idx & 7;
            ((float4*)s_he[el])[q] = ((const float4*)(he_g + (size_t)s_ed[el] * kF))[q];
        }
        for (int idx = t; idx < ce * kH; idx += 256) {
            int el = idx / kH, hh = idx - el * kH;
            s_att[el][hh] = __expf(logit_g[(size_t)s_ed[el] * kH + hh]
                                   - m_g[(size_t)node * kH + hh])
                            * invs_g[(size_t)node * kH + hh];
        }
        for (int idx = t; idx < ce * 3; idx += 256) {
            int el = idx / 3, xx = idx - el * 3;
            s_dir[el][xx] = dir_g[(size_t)s_ed[el] * 3 + xx];
        }
        __syncthreads();
        if (t < kC) {
            for (int el = 0; el < ce; el++) {
                float Tv = s_Tt[t][el];
                c0 += Tv * s_dir[el][0];
                c1 += Tv * s_dir[el][1];
                c2 += Tv * s_dir[el][2];
                hs += s_he[el][f7] * s_att[el][h7];
            }
        }
        __syncthreads();
    }

    float invc = 1.f / fmaxf((float)deg, 1.f);
    if (t < kC) {
        float m0 = c0 * invc, m1 = c1 * invc, m2 = c2 * invc;
        s_cm[0][t] = m0; s_cm[1][t] = m1; s_cm[2][t] = m2;
        s_cnsq[t] = m0 * m0 + m1 * m1 + m2 * m2;
        s_hisem[t] = hs;
    }
    if (t >= 224 && t < 256) s_hn[t - 224] = h[(size_t)node * kF + (t - 224)];
    __syncthreads();

    // pn1: 8 input-groups x 32 outputs (all 256 threads)
    int o = t & 31, g = t >> 5;
    {
        float a = 0.f;
        int cb = g * 28;
#pragma unroll
        for (int i = 0; i < 28; i++) a += s_cnsq[cb + i] * w_pn1[(cb + i) * kF + o];
        s_part[g][o] = a;
    }
    __syncthreads();
    // sp1 reduce | g1 | dv partials
    if (t < kF) {
        float a = b_pn1[t];
#pragma unroll
        for (int g2 = 0; g2 < 8; g2++) a += s_part[g2][t];
        s_sp1[t] = silu_f(a);
    } else if (t >= 64 && t < 96) {
        int oo = t - 64;
        float a = b_v1[oo];
        for (int f = 0; f < kF; f++) a += s_hn[f] * w_v1[f * kF + oo];
        s_g1[oo] = silu_f(a);
    } else if (t >= 96 && t < 192) {
        int xx = (t - 96) >> 5, ln = (t - 96) & 31;
        float a = 0.f;
        for (int c = ln; c < kC; c += 32) a += w_vmix[c] * s_cm[xx][c];
        s_pdv[xx][ln] = a;
    }
    __syncthreads();
    // pn2 -> spat | gate | dv reduce
    if (t < kF) {
        float a = b_pn2[t];
        for (int o2 = 0; o2 < kF; o2++) a += s_sp1[o2] * w_pn2[o2 * kF + t];
        s_spat[t] = silu_f(a);
    } else if (t == 64) {
        float a = 0.f;
        for (int o2 = 0; o2 < kF; o2++) a += s_g1[o2] * w_v2[o2];
        s_gate = 2.f / (1.f + __expf(-a));
    } else if (t >= 96 && t < 99) {
        int xx = t - 96;
        float a = 0.f;
#pragma unroll
        for (int ln = 0; ln < 32; ln++) a += s_pdv[xx][ln];
        s_dv[xx] = a;
    }
    __syncthreads();
    // build node_in = [h, hisem, spat]
    if (t < kF) { s_ni[t] = s_hn[t]; s_ni[kF + kC + t] = s_spat[t]; }
    if (t < kC) s_ni[kF + t] = s_hisem[t];
    __syncthreads();
    // n1: 8 input-groups x 36 rows x 32 outputs
    {
        float a = 0.f;
        int rb = g * 36;
#pragma unroll
        for (int i = 0; i < 36; i++) a += s_ni[rb + i] * w_n1[(rb + i) * kF + o];
        s_part[g][o] = a;
    }
    __syncthreads();
    if (t < kF) {
        float a = b_n1[t];
#pragma unroll
        for (int g2 = 0; g2 < 8; g2++) a += s_part[g2][t];
        s_n1[t] = silu_f(a);
    }
    __syncthreads();
    if (t < kF) {
        float a = b_n2[t];
        for (int o2 = 0; o2 < kF; o2++) a += s_n1[o2] * w_n2[o2 * kF + t];
        out_h[(size_t)node * kF + t] = s_hn[t] + silu_f(a);
    } else if (t >= 64 && t < 67) {
        int xx = t - 64;
        float vv = v[(size_t)node * 3 + xx];
        float vu = s_gate * vv + s_dv[xx];
        out_v[(size_t)node * 3 + xx] = vu;
        out_x[(size_t)node * 3 + xx] = x[(size_t)node * 3 + xx] + vu;
    }
}

// ---------------------------------------------------------------------------
extern "C" void kernel_launch(void* const* d_in, const int* in_sizes, int n_in,
                              void* d_out, int out_size, void* d_ws, size_t ws_size,
                              hipStream_t stream)
{
    const float* h      = (const float*)d_in[0];
    const float* x      = (const float*)d_in[1];
    const float* v      = (const float*)d_in[2];
    const int*   pl     = (const int*)d_in[3];
    const float* w_in   = (const float*)d_in[4];
    const float* b_in   = (const float*)d_in[5];
    const float* w_e1   = (const float*)d_in[6];
    const float* b_e1   = (const float*)d_in[7];
    const float* w_e2   = (const float*)d_in[8];
    const float* b_e2   = (const float*)d_in[9];
    const float* w_att  = (const float*)d_in[10];
    const float* b_att  = (const float*)d_in[11];
    const float* w_n1   = (const float*)d_in[12];
    const float* b_n1   = (const float*)d_in[13];
    const float* w_n2   = (const float*)d_in[14];
    const float* b_n2   = (const float*)d_in[15];
    const float* w_pn1  = (const float*)d_in[16];
    const float* b_pn1  = (const float*)d_in[17];
    const float* w_pn2  = (const float*)d_in[18];
    const float* b_pn2  = (const float*)d_in[19];
    const float* w_v1   = (const float*)d_in[20];
    const float* b_v1   = (const float*)d_in[21];
    const float* w_v2   = (const float*)d_in[22];
    const float* w_xmix = (const float*)d_in[23];
    const float* w_vmix = (const float*)d_in[24];

    const int E_ = in_sizes[3] / 2;
    const int N_ = in_sizes[0] / kF;
    const int nblk = (E_ + kM - 1) / kM;

    // Workspace (~125 MB; 16B-aligned segments first)
    char* w = (char*)d_ws;
    u16*   wxT     = (u16*)w;   w += (size_t)kC * kC * 2;
    u16*   T_g     = (u16*)w;   w += (size_t)nblk * kM * kC * 2;
    float* he_g    = (float*)w; w += (size_t)E_ * kF * 4;
    float* logit_g = (float*)w; w += (size_t)E_ * kH * 4;
    float* dir_g   = (float*)w; w += (size_t)E_ * 3 * 4;
    float* m_g     = (float*)w; w += (size_t)N_ * kH * 4;
    float* invs_g  = (float*)w; w += (size_t)N_ * kH * 4;
    int* counts    = (int*)w;   w += (size_t)N_ * 4;
    int* offs      = (int*)w;   w += (size_t)(N_ + 1) * 4;
    int* cursor    = (int*)w;   w += (size_t)N_ * 4;
    int* sorted    = (int*)w;   w += (size_t)E_ * 4;

    float* out_h = (float*)d_out;
    float* out_x = out_h + (size_t)N_ * kF;
    float* out_v = out_x + (size_t)N_ * 3;

    init_kernel<<<dim3((kC * kC + 255) / 256), dim3(256), 0, stream>>>(
        w_xmix, wxT, counts, cursor, N_);

    edge_kernel<<<dim3((E_ + 255) / 256), dim3(256), 0, stream>>>(
        h, x, pl, E_, w_in, b_in, w_e1, b_e1, w_e2, b_e2, w_att, b_att,
        he_g, logit_g, dir_g, counts);

    scan_kernel<<<dim3(1), dim3(1024), 0, stream>>>(counts, offs, N_);

    scatter_kernel<<<dim3((E_ + 255) / 256), dim3(256), 0, stream>>>(
        pl, offs, cursor, sorted, E_);

    stats_kernel<<<dim3((N_ + 3) / 4), dim3(256), 0, stream>>>(
        logit_g, offs, sorted, m_g, invs_g, N_);

    xmix_kernel<<<dim3(nblk), dim3(256), 0, stream>>>(
        he_g, logit_g, pl, sorted, m_g, invs_g, wxT, E_, T_g);

    node_kernel<<<dim3(N_), dim3(256), 0, stream>>>(
        h, x, v, T_g, he_g, logit_g, dir_g, offs, sorted, m_g, invs_g,
        w_n1, b_n1, w_n2, b_n2, w_pn1, b_pn1, w_pn2, b_pn2,
        w_v1, b_v1, w_v2, w_vmix, out_h, out_x, out_v, N_);
}

// Round 8
// 430.865 us; speedup vs baseline: 1.5404x; 1.1821x over previous
//
#include <hip/hip_runtime.h>
#include <math.h>

typedef unsigned short u16;
typedef __attribute__((ext_vector_type(8))) short bf16x8;
typedef __attribute__((ext_vector_type(4))) float f32x4;

// Problem constants (match reference)
constexpr int kF    = 32;    // nr_atom_basis
constexpr int kH    = 7;     // heads
constexpr int kC    = 224;   // F*H
constexpr int kRBF  = 50;
constexpr int kM    = 128;   // edges per xmix block
constexpr int kStr  = 232;   // xmix LDS row stride (bf16; 464B, 16B-aligned)
constexpr int kCk   = 32;    // edge chunk in node kernel
constexpr int kEM   = 128;   // edges per edge-MFMA block
constexpr int kAStr = 136;   // edge A-tile stride (bf16; 272B, 16B-aligned)
constexpr int kBStr = 40;    // t1 tile stride (bf16; 80B, 16B-aligned)
constexpr float kCut = 5.0f;
constexpr float kEps = 1e-8f;

__device__ __forceinline__ float silu_f(float a) { return a / (1.f + __expf(-a)); }
__device__ __forceinline__ float tanh_f(float x) {
    x = fminf(fmaxf(x, -15.f), 15.f);
    float e = __expf(2.f * x);
    return (e - 1.f) / (e + 1.f);
}
__device__ __forceinline__ float bf2f(u16 u) {
    union { unsigned int i; float f; } v; v.i = ((unsigned int)u) << 16; return v.f;
}
__device__ __forceinline__ u16 f2bf(float f) {
    union { float f; unsigned int i; } v; v.f = f;
    unsigned int x = v.i;
    unsigned int round = ((x >> 16) & 1u) + 0x7fffu;
    return (u16)((x + round) >> 16);
}
__device__ __forceinline__ unsigned pk2(float a, float b) {
    return (unsigned)f2bf(a) | ((unsigned)f2bf(b) << 16);
}

// ---------------------------------------------------------------------------
// K0: zero histogram/cursors; build wxT; build edge-MLP B-matrices:
// W1T[64][64] (w_in^T, cols>=50 zero), W2T[32][128] (w_e1^T, k>=115 zero),
// W3T[32][32] (w_e2^T), W24T[16][32] (= (w_e2@w_att)^T, rows>=7 zero),
// b24[7] (= b_att + b_e2@w_att).
// ---------------------------------------------------------------------------
__global__ __launch_bounds__(256) void init_kernel(
    const float* __restrict__ wx, const float* __restrict__ w_in,
    const float* __restrict__ w_e1, const float* __restrict__ w_e2,
    const float* __restrict__ w_att, const float* __restrict__ b_e2,
    const float* __restrict__ b_att,
    u16* __restrict__ wxT, u16* __restrict__ W1T, u16* __restrict__ W2T,
    u16* __restrict__ W3T, u16* __restrict__ W24T, float* __restrict__ b24,
    int* __restrict__ counts, int* __restrict__ cursor, int N_)
{
    int idx = blockIdx.x * 256 + threadIdx.x;
    if (idx < kC * kC) {
        int c = idx / kC, k = idx - c * kC;      // wxT[c][k] = wx[k][c]
        wxT[idx] = f2bf(wx[k * kC + c]);
    }
    if (idx < N_) { counts[idx] = 0; cursor[idx] = 0; }

    if (blockIdx.x == 0) {
        int t = threadIdx.x;
        for (int i = t; i < 64 * 64; i += 256) {
            int n = i >> 6, k = i & 63;
            W1T[i] = f2bf((n < kRBF) ? w_in[k * kRBF + n] : 0.f);
        }
        for (int i = t; i < 32 * 128; i += 256) {
            int n = i >> 7, k = i & 127;
            W2T[i] = f2bf((k < 115) ? w_e1[k * kF + n] : 0.f);
        }
        for (int i = t; i < 32 * 32; i += 256) {
            int n = i >> 5, k = i & 31;
            W3T[i] = f2bf(w_e2[k * kF + n]);
        }
        for (int i = t; i < 16 * 32; i += 256) {
            int n = i >> 5, k = i & 31;
            float a = 0.f;
            if (n < kH) for (int o = 0; o < kF; o++) a += w_e2[k * kF + o] * w_att[o * kH + n];
            W24T[i] = f2bf(a);
        }
        if (t < kH) {
            float a = b_att[t];
            for (int o = 0; o < kF; o++) a += b_e2[o] * w_att[o * kH + t];
            b24[t] = a;
        }
    }
}

// ---------------------------------------------------------------------------
// K1: MFMA edge kernel. 128 edges/block, 4 waves (2 row-tiles each).
// GEMM1 (h_cat@w_in) -> rbf -> GEMM2 (edge_in@w_e1) -> silu ->
// GEMM3 (t1@w_e2 -> he) and GEMM4 (t1@W24 -> logits, celu*cutoff).
// One barrier; all post-stage LDS traffic is own-rows-only.
// ---------------------------------------------------------------------------
__global__ __launch_bounds__(256) void edge_kernel(
    const float* __restrict__ h, const float* __restrict__ x,
    const int* __restrict__ pl, int E_,
    const float* __restrict__ b_in, const float* __restrict__ b_e1,
    const float* __restrict__ b_e2,
    const u16* __restrict__ W1T, const u16* __restrict__ W2T,
    const u16* __restrict__ W3T, const u16* __restrict__ W24T,
    const float* __restrict__ b24,
    float* __restrict__ he_g, float* __restrict__ logit_g,
    float* __restrict__ dir_g, int* __restrict__ counts)
{
    __shared__ __align__(16) u16 s_A[kEM][kAStr];    // 34816 B: edge_in bf16
    __shared__ __align__(16) u16 s_t1[kEM][kBStr];   // 10240 B: t1 bf16
    __shared__ float s_d[kEM];

    int t = threadIdx.x;
    int T0 = blockIdx.x * kEM;
    int w = t >> 6, lane = t & 63, quad = lane >> 4, l15 = lane & 15;

    // ---- stage: 2 threads per edge ----
    {
        int e = t >> 1, half = t & 1;
        int ge = T0 + e;
        bool val = ge < E_;
        int i = 0, j = 0;
        if (val) { i = pl[ge]; j = pl[E_ + ge]; }
        const float4* pi = (const float4*)(h + (size_t)i * kF) + half * 4;
        const float4* pj = (const float4*)(h + (size_t)j * kF) + half * 4;
#pragma unroll
        for (int q = 0; q < 4; q++) {
            float4 a = val ? pi[q] : make_float4(0.f, 0.f, 0.f, 0.f);
            float4 b = val ? pj[q] : make_float4(0.f, 0.f, 0.f, 0.f);
            unsigned* di = (unsigned*)&s_A[e][half * 16 + 4 * q];
            di[0] = pk2(a.x, a.y); di[1] = pk2(a.z, a.w);
            unsigned* dj = (unsigned*)&s_A[e][kF + half * 16 + 4 * q];
            dj[0] = pk2(b.x, b.y); dj[1] = pk2(b.z, b.w);
        }
        if (half == 0) {
            float d = 0.f;
            if (val) {
                float r0 = x[j * 3 + 0] - x[i * 3 + 0];
                float r1 = x[j * 3 + 1] - x[i * 3 + 1];
                float r2 = x[j * 3 + 2] - x[i * 3 + 2];
                d = sqrtf(r0 * r0 + r1 * r1 + r2 * r2);
                float inv = 1.0f / (d + kEps);
                dir_g[(size_t)ge * 3 + 0] = r0 * inv;
                dir_g[(size_t)ge * 3 + 1] = r1 * inv;
                dir_g[(size_t)ge * 3 + 2] = r2 * inv;
                atomicAdd(&counts[i], 1);
            }
            s_d[e] = d;
            s_A[e][114] = f2bf(d);
            s_A[e][115] = 0;
            unsigned* z = (unsigned*)&s_A[e][116];
#pragma unroll
            for (int q = 0; q < 6; q++) z[q] = 0u;
        }
    }
    __syncthreads();

    const float invw = 49.0f / kCut;   // 1/width

    // ---- GEMM1: h_cat @ w_in -> rbf -> filt into s_A cols 64..113 ----
    {
        bf16x8 a1[2][2];
#pragma unroll
        for (int rt = 0; rt < 2; rt++)
#pragma unroll
            for (int kt = 0; kt < 2; kt++)
                a1[rt][kt] = *(const bf16x8*)&s_A[32 * w + 16 * rt + l15][kt * 32 + quad * 8];
#pragma unroll
        for (int ct = 0; ct < 4; ct++) {
            int c = ct * 16 + l15;
            bf16x8 b0 = *(const bf16x8*)(W1T + (size_t)c * 64 + quad * 8);
            bf16x8 b1 = *(const bf16x8*)(W1T + (size_t)c * 64 + 32 + quad * 8);
            float bin = (c < kRBF) ? b_in[c] : 0.f;
#pragma unroll
            for (int rt = 0; rt < 2; rt++) {
                f32x4 acc = {0.f, 0.f, 0.f, 0.f};
                acc = __builtin_amdgcn_mfma_f32_16x16x32_bf16(a1[rt][0], b0, acc, 0, 0, 0);
                acc = __builtin_amdgcn_mfma_f32_16x16x32_bf16(a1[rt][1], b1, acc, 0, 0, 0);
                if (c < kRBF) {
#pragma unroll
                    for (int r = 0; r < 4; r++) {
                        int row = 32 * w + 16 * rt + quad * 4 + r;
                        float arg = s_d[row] * invw - (float)c;
                        float filt = __expf(-0.5f * arg * arg) * (acc[r] + bin);
                        s_A[row][64 + c] = f2bf(filt);
                    }
                }
            }
        }
    }

    // ---- GEMM2: edge_in @ w_e1 -> silu -> t1 (bf16 LDS) ----
    {
        bf16x8 a2[2][4];
#pragma unroll
        for (int rt = 0; rt < 2; rt++)
#pragma unroll
            for (int kt = 0; kt < 4; kt++)
                a2[rt][kt] = *(const bf16x8*)&s_A[32 * w + 16 * rt + l15][kt * 32 + quad * 8];
#pragma unroll
        for (int ct = 0; ct < 2; ct++) {
            int c = ct * 16 + l15;
            bf16x8 bb[4];
#pragma unroll
            for (int kt = 0; kt < 4; kt++)
                bb[kt] = *(const bf16x8*)(W2T + (size_t)c * 128 + kt * 32 + quad * 8);
            float be = b_e1[c];
#pragma unroll
            for (int rt = 0; rt < 2; rt++) {
                f32x4 acc = {0.f, 0.f, 0.f, 0.f};
#pragma unroll
                for (int kt = 0; kt < 4; kt++)
                    acc = __builtin_amdgcn_mfma_f32_16x16x32_bf16(a2[rt][kt], bb[kt], acc, 0, 0, 0);
#pragma unroll
                for (int r = 0; r < 4; r++) {
                    int row = 32 * w + 16 * rt + quad * 4 + r;
                    s_t1[row][c] = f2bf(silu_f(acc[r] + be));
                }
            }
        }
    }

    // ---- GEMM3 (he) + GEMM4 (logits) from t1 ----
    {
        bf16x8 a3[2];
#pragma unroll
        for (int rt = 0; rt < 2; rt++)
            a3[rt] = *(const bf16x8*)&s_t1[32 * w + 16 * rt + l15][quad * 8];

        // he = t1 @ w_e2 + b_e2 -> global fp32
#pragma unroll
        for (int ct = 0; ct < 2; ct++) {
            int c = ct * 16 + l15;
            bf16x8 b3 = *(const bf16x8*)(W3T + (size_t)c * 32 + quad * 8);
            float be = b_e2[c];
#pragma unroll
            for (int rt = 0; rt < 2; rt++) {
                f32x4 acc = {0.f, 0.f, 0.f, 0.f};
                acc = __builtin_amdgcn_mfma_f32_16x16x32_bf16(a3[rt], b3, acc, 0, 0, 0);
#pragma unroll
                for (int r = 0; r < 4; r++) {
                    int row = 32 * w + 16 * rt + quad * 4 + r;
                    int ge = T0 + row;
                    if (ge < E_) he_g[(size_t)ge * kF + c] = acc[r] + be;
                }
            }
        }
        // logits = celu(t1 @ W24 + b24, 2) * cutoff(d) -> global fp32
        {
            bf16x8 b4 = *(const bf16x8*)(W24T + (size_t)l15 * 32 + quad * 8);
            float bb = (l15 < kH) ? b24[l15] : 0.f;
#pragma unroll
            for (int rt = 0; rt < 2; rt++) {
                f32x4 acc = {0.f, 0.f, 0.f, 0.f};
                acc = __builtin_amdgcn_mfma_f32_16x16x32_bf16(a3[rt], b4, acc, 0, 0, 0);
                if (l15 < kH) {
#pragma unroll
                    for (int r = 0; r < 4; r++) {
                        int row = 32 * w + 16 * rt + quad * 4 + r;
                        int ge = T0 + row;
                        if (ge < E_) {
                            float a = acc[r] + bb;
                            a = (a >= 0.f) ? a : 2.f * (__expf(0.5f * a) - 1.f);
                            float dd = s_d[row];
                            float cut = (dd < kCut)
                                ? 0.5f * (__cosf(0.62831853071795864f * dd) + 1.f) : 0.f;
                            logit_g[(size_t)ge * kH + l15] = a * cut;
                        }
                    }
                }
            }
        }
    }
}

// ---------------------------------------------------------------------------
// K2: exclusive scan, barrier-light (1 block, 1024 threads)
// ---------------------------------------------------------------------------
__global__ __launch_bounds__(1024) void scan_kernel(
    const int* __restrict__ counts, int* __restrict__ offsets, int n)
{
    __shared__ int buf[1024];
    int t = threadIdx.x;
    int chunk = (n + 1023) >> 10;
    int lo = t * chunk;
    int s = 0;
    for (int i = 0; i < chunk; i++) {
        int g = lo + i;
        if (g < n) s += counts[g];
    }
    buf[t] = s;
    __syncthreads();
    for (int off = 1; off < 1024; off <<= 1) {
        int v = (t >= off) ? buf[t - off] : 0;
        __syncthreads();
        buf[t] += v;
        __syncthreads();
    }
    int run = buf[t] - s;
    for (int i = 0; i < chunk; i++) {
        int g = lo + i;
        if (g < n) { offsets[g] = run; run += counts[g]; }
    }
    if (t == 1023) offsets[n] = buf[1023];
}

// ---------------------------------------------------------------------------
// K3: scatter edges into CSR order
// ---------------------------------------------------------------------------
__global__ __launch_bounds__(256) void scatter_kernel(
    const int* __restrict__ pl, const int* __restrict__ offsets,
    int* __restrict__ cursor, int* __restrict__ sorted, int E_)
{
    int e = blockIdx.x * 256 + threadIdx.x;
    if (e < E_) {
        int i = pl[e];
        int p = atomicAdd(&cursor[i], 1);
        sorted[offsets[i] + p] = e;
    }
}

// ---------------------------------------------------------------------------
// K4: per-node softmax stats (wave per node, all 7 heads per edge pass)
// ---------------------------------------------------------------------------
__global__ __launch_bounds__(256) void stats_kernel(
    const float* __restrict__ logit_g, const int* __restrict__ offsets,
    const int* __restrict__ sorted,
    float* __restrict__ m_g, float* __restrict__ invs_g, int N_)
{
    int wave = threadIdx.x >> 6;
    int lane = threadIdx.x & 63;
    int node = blockIdx.x * 4 + wave;
    if (node >= N_) return;
    int base = offsets[node];
    int deg  = offsets[node + 1] - base;

    float m[kH], ss[kH];
#pragma unroll
    for (int hh = 0; hh < kH; hh++) { m[hh] = -1e30f; ss[hh] = 0.f; }
    for (int e = lane; e < deg; e += 64) {
        int ed = sorted[base + e];
        const float* lp = logit_g + (size_t)ed * kH;
#pragma unroll
        for (int hh = 0; hh < kH; hh++) {
            float vv = lp[hh];
            if (vv > m[hh]) { ss[hh] *= __expf(m[hh] - vv); m[hh] = vv; }
            ss[hh] += __expf(vv - m[hh]);
        }
    }
#pragma unroll
    for (int hh = 0; hh < kH; hh++) {
        float mm = m[hh], s2 = ss[hh];
#pragma unroll
        for (int off = 32; off >= 1; off >>= 1) {
            float mo = __shfl_xor(mm, off);
            float so = __shfl_xor(s2, off);
            float mn = fmaxf(mm, mo);
            s2 = s2 * __expf(mm - mn) + so * __expf(mo - mn);
            mm = mn;
        }
        if (lane == 0) {
            m_g[(size_t)node * kH + hh] = mm;
            invs_g[(size_t)node * kH + hh] = (s2 > 0.f) ? 1.f / s2 : 0.f;
        }
    }
}

// ---------------------------------------------------------------------------
// K5: MFMA xmix kernel. T[pos][c] = tanh(sem @ wx), bf16, CSR order.
// ---------------------------------------------------------------------------
__global__ __launch_bounds__(256) void xmix_kernel(
    const float* __restrict__ he_g, const float* __restrict__ logit_g,
    const int* __restrict__ pl, const int* __restrict__ sorted,
    const float* __restrict__ m_g, const float* __restrict__ invs_g,
    const u16* __restrict__ wxT, int E_, u16* __restrict__ T_g)
{
    __shared__ __align__(16) u16 s_buf[kM][kStr];
    __shared__ float s_att[kM][kH];
    __shared__ int   s_ed[kM];

    int t = threadIdx.x;
    int T0 = blockIdx.x * kM;

    if (t < kM) {
        int gi = T0 + t;
        s_ed[t] = (gi < E_) ? sorted[gi] : -1;
    }
    __syncthreads();

    for (int idx = t; idx < kM * kH; idx += 256) {
        int e = idx / kH, hh = idx - e * kH;
        int ed = s_ed[e];
        float a = 0.f;
        if (ed >= 0) {
            int nd = pl[ed];
            a = __expf(logit_g[(size_t)ed * kH + hh] - m_g[(size_t)nd * kH + hh])
                * invs_g[(size_t)nd * kH + hh];
        }
        s_att[e][hh] = a;
    }
    __syncthreads();

#pragma unroll
    for (int p = 0; p < kM * kF / 256; p++) {
        int idx = t + 256 * p;
        int e = idx >> 5, f = idx & 31;
        int ed = s_ed[e];
        float hv = (ed >= 0) ? he_g[(size_t)ed * kF + f] : 0.f;
        u16 sw[7];
#pragma unroll
        for (int hh = 0; hh < kH; hh++) sw[hh] = f2bf(hv * s_att[e][hh]);
        u16* dst = &s_buf[e][f * 7];
        if ((f & 1) == 0) {
            *(unsigned int*)(dst)     = (unsigned int)sw[0] | ((unsigned int)sw[1] << 16);
            *(unsigned int*)(dst + 2) = (unsigned int)sw[2] | ((unsigned int)sw[3] << 16);
            *(unsigned int*)(dst + 4) = (unsigned int)sw[4] | ((unsigned int)sw[5] << 16);
            dst[6] = sw[6];
        } else {
            dst[0] = sw[0];
            *(unsigned int*)(dst + 1) = (unsigned int)sw[1] | ((unsigned int)sw[2] << 16);
            *(unsigned int*)(dst + 3) = (unsigned int)sw[3] | ((unsigned int)sw[4] << 16);
            *(unsigned int*)(dst + 5) = (unsigned int)sw[5] | ((unsigned int)sw[6] << 16);
        }
    }
    __syncthreads();

    int w    = t >> 6;
    int lane = t & 63;
    int quad = lane >> 4;
    int l15  = lane & 15;

    bf16x8 afr[2][7];
#pragma unroll
    for (int rt = 0; rt < 2; rt++)
#pragma unroll
        for (int kt = 0; kt < 7; kt++)
            afr[rt][kt] = *(const bf16x8*)&s_buf[32 * w + 16 * rt + l15][kt * 32 + quad * 8];

    bf16x8 bA[7], bB[7];
    {
        const u16* bp = wxT + (size_t)l15 * kC + quad * 8;
#pragma unroll
        for (int kt = 0; kt < 7; kt++) bA[kt] = *(const bf16x8*)(bp + kt * 32);
    }
    __syncthreads();

    for (int ct = 0; ct < 14; ct++) {
        bf16x8* cur = (ct & 1) ? bB : bA;
        bf16x8* nxt = (ct & 1) ? bA : bB;
        if (ct < 13) {
            const u16* bp = wxT + (size_t)((ct + 1) * 16 + l15) * kC + quad * 8;
#pragma unroll
            for (int kt = 0; kt < 7; kt++) nxt[kt] = *(const bf16x8*)(bp + kt * 32);
        }
        f32x4 acc0 = {0.f, 0.f, 0.f, 0.f};
        f32x4 acc1 = {0.f, 0.f, 0.f, 0.f};
#pragma unroll
        for (int kt = 0; kt < 7; kt++) {
            acc0 = __builtin_amdgcn_mfma_f32_16x16x32_bf16(afr[0][kt], cur[kt], acc0, 0, 0, 0);
            acc1 = __builtin_amdgcn_mfma_f32_16x16x32_bf16(afr[1][kt], cur[kt], acc1, 0, 0, 0);
        }
        int colg = ct * 16 + l15;
#pragma unroll
        for (int s = 0; s < 2; s++) {
            f32x4 ac = s ? acc1 : acc0;
            int rbase = 32 * w + 16 * s + quad * 4;
#pragma unroll
            for (int r = 0; r < 4; r++)
                s_buf[rbase + r][colg] = f2bf(tanh_f(ac[r]));
        }
    }
    __syncthreads();

#pragma unroll
    for (int it = 0; it < 14; it++) {
        int idx = t + 256 * it;
        int row = idx / 28, ch = idx - row * 28;
        uint4 vv = *(const uint4*)&s_buf[row][ch * 8];
        *(uint4*)(T_g + ((size_t)(T0 + row) * kC + ch * 8)) = vv;
    }
}

// ---------------------------------------------------------------------------
// K6: one block per node — comb/hisem from T rows (transposed conflict-free
// LDS), then node MLPs parallelized over all 256 threads.
// ---------------------------------------------------------------------------
__global__ __launch_bounds__(256) void node_kernel(
    const float* __restrict__ h, const float* __restrict__ x, const float* __restrict__ v,
    const u16* __restrict__ T_g, const float* __restrict__ he_g,
    const float* __restrict__ logit_g, const float* __restrict__ dir_g,
    const int* __restrict__ offsets, const int* __restrict__ sorted,
    const float* __restrict__ m_g, const float* __restrict__ invs_g,
    const float* __restrict__ w_n1, const float* __restrict__ b_n1,
    const float* __restrict__ w_n2, const float* __restrict__ b_n2,
    const float* __restrict__ w_pn1, const float* __restrict__ b_pn1,
    const float* __restrict__ w_pn2, const float* __restrict__ b_pn2,
    const float* __restrict__ w_v1, const float* __restrict__ b_v1,
    const float* __restrict__ w_v2, const float* __restrict__ w_vmix,
    float* __restrict__ out_h, float* __restrict__ out_x, float* __restrict__ out_v,
    int N_)
{
    __shared__ float s_Tt[kC][kCk + 1];
    __shared__ float s_he[kCk][kF];
    __shared__ float s_att[kCk][kH];
    __shared__ float s_dir[kCk][3];
    __shared__ int   s_ed[kCk];
    __shared__ float s_cm[3][kC];
    __shared__ float s_cnsq[kC];
    __shared__ float s_hisem[kC];
    __shared__ float s_part[8][kF];
    __shared__ float s_pdv[3][32];
    __shared__ float s_ni[kF + kC + kF];
    __shared__ float s_hn[kF], s_sp1[kF], s_spat[kF], s_n1[kF], s_g1[kF];
    __shared__ float s_gate, s_dv[3];

    int node = blockIdx.x;
    int t = threadIdx.x;
    int base = offsets[node];
    int deg  = offsets[node + 1] - base;

    float c0 = 0.f, c1 = 0.f, c2 = 0.f, hs = 0.f;
    int f7 = t / kH, h7 = t - f7 * kH;

    for (int e0 = 0; e0 < deg; e0 += kCk) {
        int ce = min(kCk, deg - e0);
        if (t < ce) s_ed[t] = sorted[base + e0 + t];
        __syncthreads();
        for (int idx = t; idx < ce * 28; idx += 256) {
            int el = idx / 28, ch = idx - el * 28;
            uint4 vv = *(const uint4*)(T_g + ((size_t)(base + e0 + el) * kC + ch * 8));
            const u16* pv = (const u16*)&vv;
            int cb = ch * 8;
#pragma unroll
            for (int q = 0; q < 8; q++) s_Tt[cb + q][el] = bf2f(pv[q]);
        }
        for (int idx = t; idx < ce * 8; idx += 256) {
            int el = idx >> 3, q = idx & 7;
            ((float4*)s_he[el])[q] = ((const float4*)(he_g + (size_t)s_ed[el] * kF))[q];
        }
        for (int idx = t; idx < ce * kH; idx += 256) {
            int el = idx / kH, hh = idx - el * kH;
            s_att[el][hh] = __expf(logit_g[(size_t)s_ed[el] * kH + hh]
                                   - m_g[(size_t)node * kH + hh])
                            * invs_g[(size_t)node * kH + hh];
        }
        for (int idx = t; idx < ce * 3; idx += 256) {
            int el = idx / 3, xx = idx - el * 3;
            s_dir[el][xx] = dir_g[(size_t)s_ed[el] * 3 + xx];
        }
        __syncthreads();
        if (t < kC) {
            for (int el = 0; el < ce; el++) {
                float Tv = s_Tt[t][el];
                c0 += Tv * s_dir[el][0];
                c1 += Tv * s_dir[el][1];
                c2 += Tv * s_dir[el][2];
                hs += s_he[el][f7] * s_att[el][h7];
            }
        }
        __syncthreads();
    }

    float invc = 1.f / fmaxf((float)deg, 1.f);
    if (t < kC) {
        float m0 = c0 * invc, m1 = c1 * invc, m2 = c2 * invc;
        s_cm[0][t] = m0; s_cm[1][t] = m1; s_cm[2][t] = m2;
        s_cnsq[t] = m0 * m0 + m1 * m1 + m2 * m2;
        s_hisem[t] = hs;
    }
    if (t >= 224 && t < 256) s_hn[t - 224] = h[(size_t)node * kF + (t - 224)];
    __syncthreads();

    int o = t & 31, g = t >> 5;
    {
        float a = 0.f;
        int cb = g * 28;
#pragma unroll
        for (int i = 0; i < 28; i++) a += s_cnsq[cb + i] * w_pn1[(cb + i) * kF + o];
        s_part[g][o] = a;
    }
    __syncthreads();
    if (t < kF) {
        float a = b_pn1[t];
#pragma unroll
        for (int g2 = 0; g2 < 8; g2++) a += s_part[g2][t];
        s_sp1[t] = silu_f(a);
    } else if (t >= 64 && t < 96) {
        int oo = t - 64;
        float a = b_v1[oo];
        for (int f = 0; f < kF; f++) a += s_hn[f] * w_v1[f * kF + oo];
        s_g1[oo] = silu_f(a);
    } else if (t >= 96 && t < 192) {
        int xx = (t - 96) >> 5, ln = (t - 96) & 31;
        float a = 0.f;
        for (int c = ln; c < kC; c += 32) a += w_vmix[c] * s_cm[xx][c];
        s_pdv[xx][ln] = a;
    }
    __syncthreads();
    if (t < kF) {
        float a = b_pn2[t];
        for (int o2 = 0; o2 < kF; o2++) a += s_sp1[o2] * w_pn2[o2 * kF + t];
        s_spat[t] = silu_f(a);
    } else if (t == 64) {
        float a = 0.f;
        for (int o2 = 0; o2 < kF; o2++) a += s_g1[o2] * w_v2[o2];
        s_gate = 2.f / (1.f + __expf(-a));
    } else if (t >= 96 && t < 99) {
        int xx = t - 96;
        float a = 0.f;
#pragma unroll
        for (int ln = 0; ln < 32; ln++) a += s_pdv[xx][ln];
        s_dv[xx] = a;
    }
    __syncthreads();
    if (t < kF) { s_ni[t] = s_hn[t]; s_ni[kF + kC + t] = s_spat[t]; }
    if (t < kC) s_ni[kF + t] = s_hisem[t];
    __syncthreads();
    {
        float a = 0.f;
        int rb = g * 36;
#pragma unroll
        for (int i = 0; i < 36; i++) a += s_ni[rb + i] * w_n1[(rb + i) * kF + o];
        s_part[g][o] = a;
    }
    __syncthreads();
    if (t < kF) {
        float a = b_n1[t];
#pragma unroll
        for (int g2 = 0; g2 < 8; g2++) a += s_part[g2][t];
        s_n1[t] = silu_f(a);
    }
    __syncthreads();
    if (t < kF) {
        float a = b_n2[t];
        for (int o2 = 0; o2 < kF; o2++) a += s_n1[o2] * w_n2[o2 * kF + t];
        out_h[(size_t)node * kF + t] = s_hn[t] + silu_f(a);
    } else if (t >= 64 && t < 67) {
        int xx = t - 64;
        float vv = v[(size_t)node * 3 + xx];
        float vu = s_gate * vv + s_dv[xx];
        out_v[(size_t)node * 3 + xx] = vu;
        out_x[(size_t)node * 3 + xx] = x[(size_t)node * 3 + xx] + vu;
    }
}

// ---------------------------------------------------------------------------
extern "C" void kernel_launch(void* const* d_in, const int* in_sizes, int n_in,
                              void* d_out, int out_size, void* d_ws, size_t ws_size,
                              hipStream_t stream)
{
    const float* h      = (const float*)d_in[0];
    const float* x      = (const float*)d_in[1];
    const float* v      = (const float*)d_in[2];
    const int*   pl     = (const int*)d_in[3];
    const float* w_in   = (const float*)d_in[4];
    const float* b_in   = (const float*)d_in[5];
    const float* w_e1   = (const float*)d_in[6];
    const float* b_e1   = (const float*)d_in[7];
    const float* w_e2   = (const float*)d_in[8];
    const float* b_e2   = (const float*)d_in[9];
    const float* w_att  = (const float*)d_in[10];
    const float* b_att  = (const float*)d_in[11];
    const float* w_n1   = (const float*)d_in[12];
    const float* b_n1   = (const float*)d_in[13];
    const float* w_n2   = (const float*)d_in[14];
    const float* b_n2   = (const float*)d_in[15];
    const float* w_pn1  = (const float*)d_in[16];
    const float* b_pn1  = (const float*)d_in[17];
    const float* w_pn2  = (const float*)d_in[18];
    const float* b_pn2  = (const float*)d_in[19];
    const float* w_v1   = (const float*)d_in[20];
    const float* b_v1   = (const float*)d_in[21];
    const float* w_v2   = (const float*)d_in[22];
    const float* w_xmix = (const float*)d_in[23];
    const float* w_vmix = (const float*)d_in[24];

    const int E_ = in_sizes[3] / 2;
    const int N_ = in_sizes[0] / kF;
    const int nblk = (E_ + kM - 1) / kM;

    // Workspace (~125 MB; 16B-aligned segments first)
    char* w = (char*)d_ws;
    u16*   wxT     = (u16*)w;   w += (size_t)kC * kC * 2;
    u16*   W1T     = (u16*)w;   w += (size_t)64 * 64 * 2;
    u16*   W2T     = (u16*)w;   w += (size_t)32 * 128 * 2;
    u16*   W3T     = (u16*)w;   w += (size_t)32 * 32 * 2;
    u16*   W24T    = (u16*)w;   w += (size_t)16 * 32 * 2;
    float* b24     = (float*)w; w += 8 * 4;
    u16*   T_g     = (u16*)w;   w += (size_t)nblk * kM * kC * 2;
    float* he_g    = (float*)w; w += (size_t)E_ * kF * 4;
    float* logit_g = (float*)w; w += (size_t)E_ * kH * 4;
    float* dir_g   = (float*)w; w += (size_t)E_ * 3 * 4;
    float* m_g     = (float*)w; w += (size_t)N_ * kH * 4;
    float* invs_g  = (float*)w; w += (size_t)N_ * kH * 4;
    int* counts    = (int*)w;   w += (size_t)N_ * 4;
    int* offs      = (int*)w;   w += (size_t)(N_ + 1) * 4;
    int* cursor    = (int*)w;   w += (size_t)N_ * 4;
    int* sorted    = (int*)w;   w += (size_t)E_ * 4;

    float* out_h = (float*)d_out;
    float* out_x = out_h + (size_t)N_ * kF;
    float* out_v = out_x + (size_t)N_ * 3;

    init_kernel<<<dim3((kC * kC + 255) / 256), dim3(256), 0, stream>>>(
        w_xmix, w_in, w_e1, w_e2, w_att, b_e2, b_att,
        wxT, W1T, W2T, W3T, W24T, b24, counts, cursor, N_);

    edge_kernel<<<dim3((E_ + kEM - 1) / kEM), dim3(256), 0, stream>>>(
        h, x, pl, E_, b_in, b_e1, b_e2, W1T, W2T, W3T, W24T, b24,
        he_g, logit_g, dir_g, counts);

    scan_kernel<<<dim3(1), dim3(1024), 0, stream>>>(counts, offs, N_);

    scatter_kernel<<<dim3((E_ + 255) / 256), dim3(256), 0, stream>>>(
        pl, offs, cursor, sorted, E_);

    stats_kernel<<<dim3((N_ + 3) / 4), dim3(256), 0, stream>>>(
        logit_g, offs, sorted, m_g, invs_g, N_);

    xmix_kernel<<<dim3(nblk), dim3(256), 0, stream>>>(
        he_g, logit_g, pl, sorted, m_g, invs_g, wxT, E_, T_g);

    node_kernel<<<dim3(N_), dim3(256), 0, stream>>>(
        h, x, v, T_g, he_g, logit_g, dir_g, offs, sorted, m_g, invs_g,
        w_n1, b_n1, w_n2, b_n2, w_pn1, b_pn1, w_pn2, b_pn2,
        w_v1, b_v1, w_v2, w_vmix, out_h, out_x, out_v, N_);
}

// Round 9
// 406.786 us; speedup vs baseline: 1.6316x; 1.0592x over previous
//
#include <hip/hip_runtime.h>
#include <math.h>

typedef unsigned short u16;
typedef __attribute__((ext_vector_type(8))) short bf16x8;
typedef __attribute__((ext_vector_type(4))) float f32x4;

// Problem constants (match reference)
constexpr int kF    = 32;    // nr_atom_basis
constexpr int kH    = 7;     // heads
constexpr int kC    = 224;   // F*H
constexpr int kRBF  = 50;
constexpr int kM    = 128;   // edges per xmix tile
constexpr int kStr  = 232;   // xmix LDS row stride (bf16; 464B, 16B-aligned)
constexpr int kEM   = 128;   // edges per edge-MFMA block
constexpr int kAStr = 136;   // edge A-tile stride (bf16; 272B, 16B-aligned)
constexpr int kBStr = 40;    // t1 tile stride (bf16; 80B, 16B-aligned)
constexpr float kCut = 5.0f;
constexpr float kEps = 1e-8f;

__device__ __forceinline__ float silu_f(float a) { return a / (1.f + __expf(-a)); }
__device__ __forceinline__ float tanh_f(float x) {
    x = fminf(fmaxf(x, -15.f), 15.f);
    float e = __expf(2.f * x);
    return (e - 1.f) / (e + 1.f);
}
__device__ __forceinline__ float bf2f(u16 u) {
    union { unsigned int i; float f; } v; v.i = ((unsigned int)u) << 16; return v.f;
}
__device__ __forceinline__ u16 f2bf(float f) {
    union { float f; unsigned int i; } v; v.f = f;
    unsigned int x = v.i;
    unsigned int round = ((x >> 16) & 1u) + 0x7fffu;
    return (u16)((x + round) >> 16);
}
__device__ __forceinline__ unsigned pk2(float a, float b) {
    return (unsigned)f2bf(a) | ((unsigned)f2bf(b) << 16);
}

// ---------------------------------------------------------------------------
// K0: zero histogram/cursors; build wxT + edge-MLP B-matrices (see r7 notes)
// ---------------------------------------------------------------------------
__global__ __launch_bounds__(256) void init_kernel(
    const float* __restrict__ wx, const float* __restrict__ w_in,
    const float* __restrict__ w_e1, const float* __restrict__ w_e2,
    const float* __restrict__ w_att, const float* __restrict__ b_e2,
    const float* __restrict__ b_att,
    u16* __restrict__ wxT, u16* __restrict__ W1T, u16* __restrict__ W2T,
    u16* __restrict__ W3T, u16* __restrict__ W24T, float* __restrict__ b24,
    int* __restrict__ counts, int* __restrict__ cursor, int N_)
{
    int idx = blockIdx.x * 256 + threadIdx.x;
    if (idx < kC * kC) {
        int c = idx / kC, k = idx - c * kC;      // wxT[c][k] = wx[k][c]
        wxT[idx] = f2bf(wx[k * kC + c]);
    }
    if (idx < N_) { counts[idx] = 0; cursor[idx] = 0; }

    if (blockIdx.x == 0) {
        int t = threadIdx.x;
        for (int i = t; i < 64 * 64; i += 256) {
            int n = i >> 6, k = i & 63;
            W1T[i] = f2bf((n < kRBF) ? w_in[k * kRBF + n] : 0.f);
        }
        for (int i = t; i < 32 * 128; i += 256) {
            int n = i >> 7, k = i & 127;
            W2T[i] = f2bf((k < 115) ? w_e1[k * kF + n] : 0.f);
        }
        for (int i = t; i < 32 * 32; i += 256) {
            int n = i >> 5, k = i & 31;
            W3T[i] = f2bf(w_e2[k * kF + n]);
        }
        for (int i = t; i < 16 * 32; i += 256) {
            int n = i >> 5, k = i & 31;
            float a = 0.f;
            if (n < kH) for (int o = 0; o < kF; o++) a += w_e2[k * kF + o] * w_att[o * kH + n];
            W24T[i] = f2bf(a);
        }
        if (t < kH) {
            float a = b_att[t];
            for (int o = 0; o < kF; o++) a += b_e2[o] * w_att[o * kH + t];
            b24[t] = a;
        }
    }
}

// ---------------------------------------------------------------------------
// K1: MFMA edge kernel (r8-proven). GEMM1->rbf->GEMM2->silu->GEMM3/4.
// ---------------------------------------------------------------------------
__global__ __launch_bounds__(256) void edge_kernel(
    const float* __restrict__ h, const float* __restrict__ x,
    const int* __restrict__ pl, int E_,
    const float* __restrict__ b_in, const float* __restrict__ b_e1,
    const float* __restrict__ b_e2,
    const u16* __restrict__ W1T, const u16* __restrict__ W2T,
    const u16* __restrict__ W3T, const u16* __restrict__ W24T,
    const float* __restrict__ b24,
    float* __restrict__ he_g, float* __restrict__ logit_g,
    float* __restrict__ dir_g, int* __restrict__ counts)
{
    __shared__ __align__(16) u16 s_A[kEM][kAStr];
    __shared__ __align__(16) u16 s_t1[kEM][kBStr];
    __shared__ float s_d[kEM];

    int t = threadIdx.x;
    int T0 = blockIdx.x * kEM;
    int w = t >> 6, lane = t & 63, quad = lane >> 4, l15 = lane & 15;

    {
        int e = t >> 1, half = t & 1;
        int ge = T0 + e;
        bool val = ge < E_;
        int i = 0, j = 0;
        if (val) { i = pl[ge]; j = pl[E_ + ge]; }
        const float4* pi = (const float4*)(h + (size_t)i * kF) + half * 4;
        const float4* pj = (const float4*)(h + (size_t)j * kF) + half * 4;
#pragma unroll
        for (int q = 0; q < 4; q++) {
            float4 a = val ? pi[q] : make_float4(0.f, 0.f, 0.f, 0.f);
            float4 b = val ? pj[q] : make_float4(0.f, 0.f, 0.f, 0.f);
            unsigned* di = (unsigned*)&s_A[e][half * 16 + 4 * q];
            di[0] = pk2(a.x, a.y); di[1] = pk2(a.z, a.w);
            unsigned* dj = (unsigned*)&s_A[e][kF + half * 16 + 4 * q];
            dj[0] = pk2(b.x, b.y); dj[1] = pk2(b.z, b.w);
        }
        if (half == 0) {
            float d = 0.f;
            if (val) {
                float r0 = x[j * 3 + 0] - x[i * 3 + 0];
                float r1 = x[j * 3 + 1] - x[i * 3 + 1];
                float r2 = x[j * 3 + 2] - x[i * 3 + 2];
                d = sqrtf(r0 * r0 + r1 * r1 + r2 * r2);
                float inv = 1.0f / (d + kEps);
                dir_g[(size_t)ge * 3 + 0] = r0 * inv;
                dir_g[(size_t)ge * 3 + 1] = r1 * inv;
                dir_g[(size_t)ge * 3 + 2] = r2 * inv;
                atomicAdd(&counts[i], 1);
            }
            s_d[e] = d;
            s_A[e][114] = f2bf(d);
            s_A[e][115] = 0;
            unsigned* z = (unsigned*)&s_A[e][116];
#pragma unroll
            for (int q = 0; q < 6; q++) z[q] = 0u;
        }
    }
    __syncthreads();

    const float invw = 49.0f / kCut;

    {   // GEMM1: h_cat @ w_in -> rbf -> filt
        bf16x8 a1[2][2];
#pragma unroll
        for (int rt = 0; rt < 2; rt++)
#pragma unroll
            for (int kt = 0; kt < 2; kt++)
                a1[rt][kt] = *(const bf16x8*)&s_A[32 * w + 16 * rt + l15][kt * 32 + quad * 8];
#pragma unroll
        for (int ct = 0; ct < 4; ct++) {
            int c = ct * 16 + l15;
            bf16x8 b0 = *(const bf16x8*)(W1T + (size_t)c * 64 + quad * 8);
            bf16x8 b1 = *(const bf16x8*)(W1T + (size_t)c * 64 + 32 + quad * 8);
            float bin = (c < kRBF) ? b_in[c] : 0.f;
#pragma unroll
            for (int rt = 0; rt < 2; rt++) {
                f32x4 acc = {0.f, 0.f, 0.f, 0.f};
                acc = __builtin_amdgcn_mfma_f32_16x16x32_bf16(a1[rt][0], b0, acc, 0, 0, 0);
                acc = __builtin_amdgcn_mfma_f32_16x16x32_bf16(a1[rt][1], b1, acc, 0, 0, 0);
                if (c < kRBF) {
#pragma unroll
                    for (int r = 0; r < 4; r++) {
                        int row = 32 * w + 16 * rt + quad * 4 + r;
                        float arg = s_d[row] * invw - (float)c;
                        float filt = __expf(-0.5f * arg * arg) * (acc[r] + bin);
                        s_A[row][64 + c] = f2bf(filt);
                    }
                }
            }
        }
    }

    {   // GEMM2: edge_in @ w_e1 -> silu -> t1
        bf16x8 a2[2][4];
#pragma unroll
        for (int rt = 0; rt < 2; rt++)
#pragma unroll
            for (int kt = 0; kt < 4; kt++)
                a2[rt][kt] = *(const bf16x8*)&s_A[32 * w + 16 * rt + l15][kt * 32 + quad * 8];
#pragma unroll
        for (int ct = 0; ct < 2; ct++) {
            int c = ct * 16 + l15;
            bf16x8 bb[4];
#pragma unroll
            for (int kt = 0; kt < 4; kt++)
                bb[kt] = *(const bf16x8*)(W2T + (size_t)c * 128 + kt * 32 + quad * 8);
            float be = b_e1[c];
#pragma unroll
            for (int rt = 0; rt < 2; rt++) {
                f32x4 acc = {0.f, 0.f, 0.f, 0.f};
#pragma unroll
                for (int kt = 0; kt < 4; kt++)
                    acc = __builtin_amdgcn_mfma_f32_16x16x32_bf16(a2[rt][kt], bb[kt], acc, 0, 0, 0);
#pragma unroll
                for (int r = 0; r < 4; r++) {
                    int row = 32 * w + 16 * rt + quad * 4 + r;
                    s_t1[row][c] = f2bf(silu_f(acc[r] + be));
                }
            }
        }
    }

    {   // GEMM3 (he) + GEMM4 (logits)
        bf16x8 a3[2];
#pragma unroll
        for (int rt = 0; rt < 2; rt++)
            a3[rt] = *(const bf16x8*)&s_t1[32 * w + 16 * rt + l15][quad * 8];

#pragma unroll
        for (int ct = 0; ct < 2; ct++) {
            int c = ct * 16 + l15;
            bf16x8 b3 = *(const bf16x8*)(W3T + (size_t)c * 32 + quad * 8);
            float be = b_e2[c];
#pragma unroll
            for (int rt = 0; rt < 2; rt++) {
                f32x4 acc = {0.f, 0.f, 0.f, 0.f};
                acc = __builtin_amdgcn_mfma_f32_16x16x32_bf16(a3[rt], b3, acc, 0, 0, 0);
#pragma unroll
                for (int r = 0; r < 4; r++) {
                    int row = 32 * w + 16 * rt + quad * 4 + r;
                    int ge = T0 + row;
                    if (ge < E_) he_g[(size_t)ge * kF + c] = acc[r] + be;
                }
            }
        }
        {
            bf16x8 b4 = *(const bf16x8*)(W24T + (size_t)l15 * 32 + quad * 8);
            float bb = (l15 < kH) ? b24[l15] : 0.f;
#pragma unroll
            for (int rt = 0; rt < 2; rt++) {
                f32x4 acc = {0.f, 0.f, 0.f, 0.f};
                acc = __builtin_amdgcn_mfma_f32_16x16x32_bf16(a3[rt], b4, acc, 0, 0, 0);
                if (l15 < kH) {
#pragma unroll
                    for (int r = 0; r < 4; r++) {
                        int row = 32 * w + 16 * rt + quad * 4 + r;
                        int ge = T0 + row;
                        if (ge < E_) {
                            float a = acc[r] + bb;
                            a = (a >= 0.f) ? a : 2.f * (__expf(0.5f * a) - 1.f);
                            float dd = s_d[row];
                            float cut = (dd < kCut)
                                ? 0.5f * (__cosf(0.62831853071795864f * dd) + 1.f) : 0.f;
                            logit_g[(size_t)ge * kH + l15] = a * cut;
                        }
                    }
                }
            }
        }
    }
}

// ---------------------------------------------------------------------------
// K2: exclusive scan, barrier-light
// ---------------------------------------------------------------------------
__global__ __launch_bounds__(1024) void scan_kernel(
    const int* __restrict__ counts, int* __restrict__ offsets, int n)
{
    __shared__ int buf[1024];
    int t = threadIdx.x;
    int chunk = (n + 1023) >> 10;
    int lo = t * chunk;
    int s = 0;
    for (int i = 0; i < chunk; i++) {
        int g = lo + i;
        if (g < n) s += counts[g];
    }
    buf[t] = s;
    __syncthreads();
    for (int off = 1; off < 1024; off <<= 1) {
        int v = (t >= off) ? buf[t - off] : 0;
        __syncthreads();
        buf[t] += v;
        __syncthreads();
    }
    int run = buf[t] - s;
    for (int i = 0; i < chunk; i++) {
        int g = lo + i;
        if (g < n) { offsets[g] = run; run += counts[g]; }
    }
    if (t == 1023) offsets[n] = buf[1023];
}

// ---------------------------------------------------------------------------
// K3: scatter edges into CSR order
// ---------------------------------------------------------------------------
__global__ __launch_bounds__(256) void scatter_kernel(
    const int* __restrict__ pl, const int* __restrict__ offsets,
    int* __restrict__ cursor, int* __restrict__ sorted, int E_)
{
    int e = blockIdx.x * 256 + threadIdx.x;
    if (e < E_) {
        int i = pl[e];
        int p = atomicAdd(&cursor[i], 1);
        sorted[offsets[i] + p] = e;
    }
}

// ---------------------------------------------------------------------------
// K4: per-node softmax stats (wave per node)
// ---------------------------------------------------------------------------
__global__ __launch_bounds__(256) void stats_kernel(
    const float* __restrict__ logit_g, const int* __restrict__ offsets,
    const int* __restrict__ sorted,
    float* __restrict__ m_g, float* __restrict__ invs_g, int N_)
{
    int wave = threadIdx.x >> 6;
    int lane = threadIdx.x & 63;
    int node = blockIdx.x * 4 + wave;
    if (node >= N_) return;
    int base = offsets[node];
    int deg  = offsets[node + 1] - base;

    float m[kH], ss[kH];
#pragma unroll
    for (int hh = 0; hh < kH; hh++) { m[hh] = -1e30f; ss[hh] = 0.f; }
    for (int e = lane; e < deg; e += 64) {
        int ed = sorted[base + e];
        const float* lp = logit_g + (size_t)ed * kH;
#pragma unroll
        for (int hh = 0; hh < kH; hh++) {
            float vv = lp[hh];
            if (vv > m[hh]) { ss[hh] *= __expf(m[hh] - vv); m[hh] = vv; }
            ss[hh] += __expf(vv - m[hh]);
        }
    }
#pragma unroll
    for (int hh = 0; hh < kH; hh++) {
        float mm = m[hh], s2 = ss[hh];
#pragma unroll
        for (int off = 32; off >= 1; off >>= 1) {
            float mo = __shfl_xor(mm, off);
            float so = __shfl_xor(s2, off);
            float mn = fmaxf(mm, mo);
            s2 = s2 * __expf(mm - mn) + so * __expf(mo - mn);
            mm = mn;
        }
        if (lane == 0) {
            m_g[(size_t)node * kH + hh] = mm;
            invs_g[(size_t)node * kH + hh] = (s2 > 0.f) ? 1.f / s2 : 0.f;
        }
    }
}

// ---------------------------------------------------------------------------
// K5: MFMA xmix kernel + in-tile comb/hisem reduction (no T round-trip).
// Runs complete in this tile -> direct nodeacc write; boundary runs -> bpart.
// ---------------------------------------------------------------------------
__global__ __launch_bounds__(256) void xmix_kernel(
    const float* __restrict__ he_g, const float* __restrict__ logit_g,
    const float* __restrict__ dir_g,
    const int* __restrict__ pl, const int* __restrict__ sorted,
    const float* __restrict__ m_g, const float* __restrict__ invs_g,
    const u16* __restrict__ wxT, int E_,
    float* __restrict__ nodeacc, float* __restrict__ bpart, int* __restrict__ bid)
{
    __shared__ __align__(16) u16 s_buf[kM][kStr];   // sem, then T
    __shared__ float s_att[kM][kH];
    __shared__ float s_dir[kM][3];
    __shared__ int   s_ed[kM];
    __shared__ int   s_node[kM];
    __shared__ int   s_c0f, s_c1f;

    int t = threadIdx.x;
    int T0 = blockIdx.x * kM;
    int cp = min(kM, E_ - T0);

    if (t < kM) {
        int gi = T0 + t;
        int ed = (gi < E_) ? sorted[gi] : -1;
        s_ed[t] = ed;
        s_node[t] = (ed >= 0) ? pl[ed] : -1;
    }
    __syncthreads();

    if (t == 0) {
        int c0 = (T0 == 0) || (pl[sorted[T0 - 1]] != s_node[0]);
        int c1 = (T0 + cp >= E_) || (pl[sorted[T0 + cp]] != s_node[cp - 1]);
        s_c0f = c0; s_c1f = c1;
        int nf = s_node[0], nl = s_node[cp - 1];
        int b0 = -1, b1 = -1;
        if (nf == nl) { if (!c0) b0 = nf; else if (!c1) b1 = nf; }
        else { if (!c0) b0 = nf; if (!c1) b1 = nl; }
        bid[2 * blockIdx.x] = b0;
        bid[2 * blockIdx.x + 1] = b1;
    }

    for (int idx = t; idx < kM * kH; idx += 256) {
        int e = idx / kH, hh = idx - e * kH;
        int ed = s_ed[e];
        float a = 0.f;
        if (ed >= 0) {
            int nd = s_node[e];
            a = __expf(logit_g[(size_t)ed * kH + hh] - m_g[(size_t)nd * kH + hh])
                * invs_g[(size_t)nd * kH + hh];
        }
        s_att[e][hh] = a;
    }
    for (int idx = t; idx < cp * 3; idx += 256) {
        int e = idx / 3, xx = idx - e * 3;
        s_dir[e][xx] = dir_g[(size_t)s_ed[e] * 3 + xx];
    }
    __syncthreads();

    // sem build (bf16)
#pragma unroll
    for (int p = 0; p < kM * kF / 256; p++) {
        int idx = t + 256 * p;
        int e = idx >> 5, f = idx & 31;
        int ed = s_ed[e];
        float hv = (ed >= 0) ? he_g[(size_t)ed * kF + f] : 0.f;
        u16 sw[7];
#pragma unroll
        for (int hh = 0; hh < kH; hh++) sw[hh] = f2bf(hv * s_att[e][hh]);
        u16* dst = &s_buf[e][f * 7];
        if ((f & 1) == 0) {
            *(unsigned int*)(dst)     = (unsigned int)sw[0] | ((unsigned int)sw[1] << 16);
            *(unsigned int*)(dst + 2) = (unsigned int)sw[2] | ((unsigned int)sw[3] << 16);
            *(unsigned int*)(dst + 4) = (unsigned int)sw[4] | ((unsigned int)sw[5] << 16);
            dst[6] = sw[6];
        } else {
            dst[0] = sw[0];
            *(unsigned int*)(dst + 1) = (unsigned int)sw[1] | ((unsigned int)sw[2] << 16);
            *(unsigned int*)(dst + 3) = (unsigned int)sw[3] | ((unsigned int)sw[4] << 16);
            *(unsigned int*)(dst + 5) = (unsigned int)sw[5] | ((unsigned int)sw[6] << 16);
        }
    }
    __syncthreads();

    // hisem walk (run-compressed; k=3 slot of nodeacc/bpart)
    if (t < kC) {
        float run = 0.f; int rs = 0;
        for (int e = 0; e < cp; e++) {
            if (s_node[e] != s_node[rs]) {
                int n = s_node[rs];
                bool t0 = (rs == 0);
                bool comp = (!t0 || s_c0f);   // interior end (not touching cp-1)
                if (comp) nodeacc[(size_t)n * 896 + 672 + t] = run;
                else bpart[((size_t)(2 * blockIdx.x) + 0) * 896 + 672 + t] = run;
                run = 0.f; rs = e;
            }
            run += bf2f(s_buf[e][t]);
        }
        {   // final run (touches end)
            int n = s_node[rs];
            bool t0 = (rs == 0);
            bool comp = (!t0 || s_c0f) && s_c1f;
            if (comp) nodeacc[(size_t)n * 896 + 672 + t] = run;
            else {
                int slot = (t0 && !s_c0f) ? 0 : 1;
                bpart[((size_t)(2 * blockIdx.x) + slot) * 896 + 672 + t] = run;
            }
        }
    }

    // MFMA fragments
    int w    = t >> 6;
    int lane = t & 63;
    int quad = lane >> 4;
    int l15  = lane & 15;

    bf16x8 afr[2][7];
#pragma unroll
    for (int rt = 0; rt < 2; rt++)
#pragma unroll
        for (int kt = 0; kt < 7; kt++)
            afr[rt][kt] = *(const bf16x8*)&s_buf[32 * w + 16 * rt + l15][kt * 32 + quad * 8];

    bf16x8 bA[7], bB[7];
    {
        const u16* bp = wxT + (size_t)l15 * kC + quad * 8;
#pragma unroll
        for (int kt = 0; kt < 7; kt++) bA[kt] = *(const bf16x8*)(bp + kt * 32);
    }
    __syncthreads();   // hisem walk + A-loads done before T write-back

    for (int ct = 0; ct < 14; ct++) {
        bf16x8* cur = (ct & 1) ? bB : bA;
        bf16x8* nxt = (ct & 1) ? bA : bB;
        if (ct < 13) {
            const u16* bp = wxT + (size_t)((ct + 1) * 16 + l15) * kC + quad * 8;
#pragma unroll
            for (int kt = 0; kt < 7; kt++) nxt[kt] = *(const bf16x8*)(bp + kt * 32);
        }
        f32x4 acc0 = {0.f, 0.f, 0.f, 0.f};
        f32x4 acc1 = {0.f, 0.f, 0.f, 0.f};
#pragma unroll
        for (int kt = 0; kt < 7; kt++) {
            acc0 = __builtin_amdgcn_mfma_f32_16x16x32_bf16(afr[0][kt], cur[kt], acc0, 0, 0, 0);
            acc1 = __builtin_amdgcn_mfma_f32_16x16x32_bf16(afr[1][kt], cur[kt], acc1, 0, 0, 0);
        }
        int colg = ct * 16 + l15;
#pragma unroll
        for (int s = 0; s < 2; s++) {
            f32x4 ac = s ? acc1 : acc0;
            int rbase = 32 * w + 16 * s + quad * 4;
#pragma unroll
            for (int r = 0; r < 4; r++)
                s_buf[rbase + r][colg] = f2bf(tanh_f(ac[r]));
        }
    }
    __syncthreads();

    // comb walk: T * dir, run-compressed (k=0..2)
    if (t < kC) {
        float r0 = 0.f, r1 = 0.f, r2 = 0.f; int rs = 0;
        for (int e = 0; e < cp; e++) {
            if (s_node[e] != s_node[rs]) {
                int n = s_node[rs];
                bool t0 = (rs == 0);
                bool comp = (!t0 || s_c0f);
                if (comp) {
                    float* p = nodeacc + (size_t)n * 896;
                    p[t] = r0; p[224 + t] = r1; p[448 + t] = r2;
                } else {
                    float* p = bpart + ((size_t)(2 * blockIdx.x) + 0) * 896;
                    p[t] = r0; p[224 + t] = r1; p[448 + t] = r2;
                }
                r0 = r1 = r2 = 0.f; rs = e;
            }
            float T = bf2f(s_buf[e][t]);
            r0 += T * s_dir[e][0];
            r1 += T * s_dir[e][1];
            r2 += T * s_dir[e][2];
        }
        {
            int n = s_node[rs];
            bool t0 = (rs == 0);
            bool comp = (!t0 || s_c0f) && s_c1f;
            if (comp) {
                float* p = nodeacc + (size_t)n * 896;
                p[t] = r0; p[224 + t] = r1; p[448 + t] = r2;
            } else {
                int slot = (t0 && !s_c0f) ? 0 : 1;
                float* p = bpart + ((size_t)(2 * blockIdx.x) + slot) * 896;
                p[t] = r0; p[224 + t] = r1; p[448 + t] = r2;
            }
        }
    }
}

// ---------------------------------------------------------------------------
// K6: node epilogue. 4 nodes/block; gather nodeacc/bpart; MLPs with
// weight-value reuse across the 4 nodes (registers), L2 traffic /4.
// ---------------------------------------------------------------------------
__global__ __launch_bounds__(256) void node_kernel(
    const float* __restrict__ h, const float* __restrict__ x, const float* __restrict__ v,
    const float* __restrict__ nodeacc, const float* __restrict__ bpart,
    const int* __restrict__ bid, const int* __restrict__ offs,
    const float* __restrict__ w_n1, const float* __restrict__ b_n1,
    const float* __restrict__ w_n2, const float* __restrict__ b_n2,
    const float* __restrict__ w_pn1, const float* __restrict__ b_pn1,
    const float* __restrict__ w_pn2, const float* __restrict__ b_pn2,
    const float* __restrict__ w_v1, const float* __restrict__ b_v1,
    const float* __restrict__ w_v2, const float* __restrict__ w_vmix,
    float* __restrict__ out_h, float* __restrict__ out_x, float* __restrict__ out_v,
    int N_)
{
    __shared__ float s_cm[4][3][kC];
    __shared__ float s_cnsq[4][kC];
    __shared__ float s_ni[4][288];          // [h | hisem | spat]
    __shared__ float s_part[8][4][kF];
    __shared__ float s_hn[4][kF], s_sp1[4][kF], s_spat[4][kF], s_n1v[4][kF], s_g1[4][kF];
    __shared__ float s_pdv[4][3][8];
    __shared__ float s_gate[4], s_dv[4][3];

    int t = threadIdx.x;
    int n0 = blockIdx.x * 4;

    if (t < kC) {
        for (int nd = 0; nd < 4; nd++) {
            int node = n0 + nd;
            if (node >= N_) break;
            int base = offs[node], end = offs[node + 1];
            int deg = end - base;
            float a0 = 0.f, a1 = 0.f, a2 = 0.f, hh = 0.f;
            if (deg > 0) {
                int tlo = base >> 7, thi = (end - 1) >> 7;
                if (tlo == thi) {
                    const float* p = nodeacc + (size_t)node * 896;
                    a0 = p[t]; a1 = p[224 + t]; a2 = p[448 + t]; hh = p[672 + t];
                } else {
                    for (int tt = tlo; tt <= thi; tt++) {
#pragma unroll
                        for (int s = 0; s < 2; s++) {
                            if (bid[2 * tt + s] == node) {
                                const float* p = bpart + (size_t)(2 * tt + s) * 896;
                                a0 += p[t]; a1 += p[224 + t]; a2 += p[448 + t]; hh += p[672 + t];
                            }
                        }
                    }
                }
            }
            float invc = 1.f / fmaxf((float)deg, 1.f);
            float m0 = a0 * invc, m1 = a1 * invc, m2 = a2 * invc;
            s_cm[nd][0][t] = m0; s_cm[nd][1][t] = m1; s_cm[nd][2][t] = m2;
            s_cnsq[nd][t] = m0 * m0 + m1 * m1 + m2 * m2;
            s_ni[nd][kF + t] = hh;
        }
    } else {
        int ln = t - 224;   // 0..31
        for (int nd = 0; nd < 4; nd++) {
            int node = n0 + nd;
            float hv = (node < N_) ? h[(size_t)node * kF + ln] : 0.f;
            s_hn[nd][ln] = hv;
            s_ni[nd][ln] = hv;
        }
    }
    __syncthreads();

    int o = t & 31, g = t >> 5;
    {   // pn1 partials, 4 nodes per weight load
        float acc[4] = {0.f, 0.f, 0.f, 0.f};
        int cb = g * 28;
        for (int i = 0; i < 28; i++) {
            float wv = w_pn1[(cb + i) * kF + o];
#pragma unroll
            for (int nd = 0; nd < 4; nd++) acc[nd] += s_cnsq[nd][cb + i] * wv;
        }
#pragma unroll
        for (int nd = 0; nd < 4; nd++) s_part[g][nd][o] = acc[nd];
    }
    __syncthreads();
    if (t < 128) {
        int nd = t >> 5;
        float a = b_pn1[o];
#pragma unroll
        for (int g2 = 0; g2 < 8; g2++) a += s_part[g2][nd][o];
        s_sp1[nd][o] = silu_f(a);
    } else {
        int nd = (t - 128) >> 5;
        float a = b_v1[o];
        for (int f = 0; f < kF; f++) a += s_hn[nd][f] * w_v1[f * kF + o];
        s_g1[nd][o] = silu_f(a);
    }
    __syncthreads();
    if (t < 128) {
        int nd = t >> 5;
        float a = b_pn2[o];
        for (int o2 = 0; o2 < kF; o2++) a += s_sp1[nd][o2] * w_pn2[o2 * kF + o];
        s_spat[nd][o] = silu_f(a);
    } else if (t < 132) {
        int nd = t - 128;
        float a = 0.f;
        for (int o2 = 0; o2 < kF; o2++) a += s_g1[nd][o2] * w_v2[o2];
        s_gate[nd] = 2.f / (1.f + __expf(-a));
    } else if (t >= 160) {   // 96 threads: dv partials (4 nodes x 3 dims x 8 lanes)
        int q = t - 160; int nd = q / 24; int r = q - nd * 24;
        int xx = r >> 3, ln = r & 7;
        float a = 0.f;
        for (int c = ln; c < kC; c += 8) a += w_vmix[c] * s_cm[nd][xx][c];
        s_pdv[nd][xx][ln] = a;
    }
    __syncthreads();
    if (t < 128) {
        int nd = t >> 5;
        s_ni[nd][kF + kC + o] = s_spat[nd][o];
    } else if (t < 140) {
        int q = t - 128; int nd = q / 3; int xx = q - nd * 3;
        float a = 0.f;
#pragma unroll
        for (int ln = 0; ln < 8; ln++) a += s_pdv[nd][xx][ln];
        s_dv[nd][xx] = a;
    }
    __syncthreads();
    {   // n1 partials: 8 groups x 36 rows
        float acc[4] = {0.f, 0.f, 0.f, 0.f};
        int rb = g * 36;
        for (int i = 0; i < 36; i++) {
            float wv = w_n1[(rb + i) * kF + o];
#pragma unroll
            for (int nd = 0; nd < 4; nd++) acc[nd] += s_ni[nd][rb + i] * wv;
        }
#pragma unroll
        for (int nd = 0; nd < 4; nd++) s_part[g][nd][o] = acc[nd];
    }
    __syncthreads();
    if (t < 128) {
        int nd = t >> 5;
        float a = b_n1[o];
#pragma unroll
        for (int g2 = 0; g2 < 8; g2++) a += s_part[g2][nd][o];
        s_n1v[nd][o] = silu_f(a);
    }
    __syncthreads();
    if (t < 128) {
        int nd = t >> 5; int node = n0 + nd;
        if (node < N_) {
            float a = b_n2[o];
            for (int o2 = 0; o2 < kF; o2++) a += s_n1v[nd][o2] * w_n2[o2 * kF + o];
            out_h[(size_t)node * kF + o] = s_hn[nd][o] + silu_f(a);
        }
    } else if (t < 140) {
        int q = t - 128; int nd = q / 3; int xx = q - nd * 3;
        int node = n0 + nd;
        if (node < N_) {
            float vv = v[(size_t)node * 3 + xx];
            float vu = s_gate[nd] * vv + s_dv[nd][xx];
            out_v[(size_t)node * 3 + xx] = vu;
            out_x[(size_t)node * 3 + xx] = x[(size_t)node * 3 + xx] + vu;
        }
    }
}

// ---------------------------------------------------------------------------
extern "C" void kernel_launch(void* const* d_in, const int* in_sizes, int n_in,
                              void* d_out, int out_size, void* d_ws, size_t ws_size,
                              hipStream_t stream)
{
    const float* h      = (const float*)d_in[0];
    const float* x      = (const float*)d_in[1];
    const float* v      = (const float*)d_in[2];
    const int*   pl     = (const int*)d_in[3];
    const float* w_in   = (const float*)d_in[4];
    const float* b_in   = (const float*)d_in[5];
    const float* w_e1   = (const float*)d_in[6];
    const float* b_e1   = (const float*)d_in[7];
    const float* w_e2   = (const float*)d_in[8];
    const float* b_e2   = (const float*)d_in[9];
    const float* w_att  = (const float*)d_in[10];
    const float* b_att  = (const float*)d_in[11];
    const float* w_n1   = (const float*)d_in[12];
    const float* b_n1   = (const float*)d_in[13];
    const float* w_n2   = (const float*)d_in[14];
    const float* b_n2   = (const float*)d_in[15];
    const float* w_pn1  = (const float*)d_in[16];
    const float* b_pn1  = (const float*)d_in[17];
    const float* w_pn2  = (const float*)d_in[18];
    const float* b_pn2  = (const float*)d_in[19];
    const float* w_v1   = (const float*)d_in[20];
    const float* b_v1   = (const float*)d_in[21];
    const float* w_v2   = (const float*)d_in[22];
    const float* w_xmix = (const float*)d_in[23];
    const float* w_vmix = (const float*)d_in[24];

    const int E_ = in_sizes[3] / 2;
    const int N_ = in_sizes[0] / kF;
    const int nblk = (E_ + kM - 1) / kM;

    // Workspace (~83 MB; 16B-aligned segments first)
    char* w = (char*)d_ws;
    u16*   wxT     = (u16*)w;   w += (size_t)kC * kC * 2;
    u16*   W1T     = (u16*)w;   w += (size_t)64 * 64 * 2;
    u16*   W2T     = (u16*)w;   w += (size_t)32 * 128 * 2;
    u16*   W3T     = (u16*)w;   w += (size_t)32 * 32 * 2;
    u16*   W24T    = (u16*)w;   w += (size_t)16 * 32 * 2;
    float* b24     = (float*)w; w += 8 * 4;
    float* he_g    = (float*)w; w += (size_t)E_ * kF * 4;
    float* logit_g = (float*)w; w += (size_t)E_ * kH * 4;
    float* dir_g   = (float*)w; w += (size_t)E_ * 3 * 4;
    float* m_g     = (float*)w; w += (size_t)N_ * kH * 4;
    float* invs_g  = (float*)w; w += (size_t)N_ * kH * 4;
    float* nodeacc = (float*)w; w += (size_t)N_ * 896 * 4;       // [N][4][224]
    float* bpart   = (float*)w; w += (size_t)2 * nblk * 896 * 4; // [2*nblk][4][224]
    int*   bid     = (int*)w;   w += (size_t)2 * nblk * 4;
    int* counts    = (int*)w;   w += (size_t)N_ * 4;
    int* offs      = (int*)w;   w += (size_t)(N_ + 1) * 4;
    int* cursor    = (int*)w;   w += (size_t)N_ * 4;
    int* sorted    = (int*)w;   w += (size_t)E_ * 4;

    float* out_h = (float*)d_out;
    float* out_x = out_h + (size_t)N_ * kF;
    float* out_v = out_x + (size_t)N_ * 3;

    init_kernel<<<dim3((kC * kC + 255) / 256), dim3(256), 0, stream>>>(
        w_xmix, w_in, w_e1, w_e2, w_att, b_e2, b_att,
        wxT, W1T, W2T, W3T, W24T, b24, counts, cursor, N_);

    edge_kernel<<<dim3((E_ + kEM - 1) / kEM), dim3(256), 0, stream>>>(
        h, x, pl, E_, b_in, b_e1, b_e2, W1T, W2T, W3T, W24T, b24,
        he_g, logit_g, dir_g, counts);

    scan_kernel<<<dim3(1), dim3(1024), 0, stream>>>(counts, offs, N_);

    scatter_kernel<<<dim3((E_ + 255) / 256), dim3(256), 0, stream>>>(
        pl, offs, cursor, sorted, E_);

    stats_kernel<<<dim3((N_ + 3) / 4), dim3(256), 0, stream>>>(
        logit_g, offs, sorted, m_g, invs_g, N_);

    xmix_kernel<<<dim3(nblk), dim3(256), 0, stream>>>(
        he_g, logit_g, dir_g, pl, sorted, m_g, invs_g, wxT, E_,
        nodeacc, bpart, bid);

    node_kernel<<<dim3((N_ + 3) / 4), dim3(256), 0, stream>>>(
        h, x, v, nodeacc, bpart, bid, offs,
        w_n1, b_n1, w_n2, b_n2, w_pn1, b_pn1, w_pn2, b_pn2,
        w_v1, b_v1, w_v2, w_vmix, out_h, out_x, out_v, N_);
}

// Round 10
// 361.662 us; speedup vs baseline: 1.8352x; 1.1248x over previous
//
#include <hip/hip_runtime.h>
#include <math.h>

typedef unsigned short u16;
typedef __attribute__((ext_vector_type(8))) short bf16x8;
typedef __attribute__((ext_vector_type(4))) float f32x4;

// Problem constants (match reference)
constexpr int kF    = 32;    // nr_atom_basis
constexpr int kH    = 7;     // heads
constexpr int kC    = 224;   // F*H
constexpr int kRBF  = 50;
constexpr int kM    = 128;   // edges per xmix tile
constexpr int kStr  = 232;   // xmix LDS row stride (bf16; 464B, 16B-aligned)
constexpr int kEM   = 128;   // edges per edge-MFMA block
constexpr int kAStr = 136;   // edge A-tile stride (bf16; 272B, 16B-aligned)
constexpr int kBStr = 40;    // t1 tile stride (bf16; 80B, 16B-aligned)
constexpr float kCut = 5.0f;
constexpr float kEps = 1e-8f;

__device__ __forceinline__ float silu_f(float a) { return a / (1.f + __expf(-a)); }
__device__ __forceinline__ float tanh_f(float x) {
    x = fminf(fmaxf(x, -15.f), 15.f);
    float e = __expf(2.f * x);
    return (e - 1.f) / (e + 1.f);
}
__device__ __forceinline__ float bf2f(u16 u) {
    union { unsigned int i; float f; } v; v.i = ((unsigned int)u) << 16; return v.f;
}
__device__ __forceinline__ u16 f2bf(float f) {
    union { float f; unsigned int i; } v; v.f = f;
    unsigned int x = v.i;
    unsigned int round = ((x >> 16) & 1u) + 0x7fffu;
    return (u16)((x + round) >> 16);
}
__device__ __forceinline__ unsigned pk2(float a, float b) {
    return (unsigned)f2bf(a) | ((unsigned)f2bf(b) << 16);
}

// ---------------------------------------------------------------------------
// K0: zero histogram/cursors; build wxT + edge-MLP B-matrices
// ---------------------------------------------------------------------------
__global__ __launch_bounds__(256) void init_kernel(
    const float* __restrict__ wx, const float* __restrict__ w_in,
    const float* __restrict__ w_e1, const float* __restrict__ w_e2,
    const float* __restrict__ w_att, const float* __restrict__ b_e2,
    const float* __restrict__ b_att,
    u16* __restrict__ wxT, u16* __restrict__ W1T, u16* __restrict__ W2T,
    u16* __restrict__ W3T, u16* __restrict__ W24T, float* __restrict__ b24,
    int* __restrict__ counts, int* __restrict__ cursor, int N_)
{
    int idx = blockIdx.x * 256 + threadIdx.x;
    if (idx < kC * kC) {
        int c = idx / kC, k = idx - c * kC;      // wxT[c][k] = wx[k][c]
        wxT[idx] = f2bf(wx[k * kC + c]);
    }
    if (idx < N_) { counts[idx] = 0; cursor[idx] = 0; }

    if (blockIdx.x == 0) {
        int t = threadIdx.x;
        for (int i = t; i < 64 * 64; i += 256) {
            int n = i >> 6, k = i & 63;
            W1T[i] = f2bf((n < kRBF) ? w_in[k * kRBF + n] : 0.f);
        }
        for (int i = t; i < 32 * 128; i += 256) {
            int n = i >> 7, k = i & 127;
            W2T[i] = f2bf((k < 115) ? w_e1[k * kF + n] : 0.f);
        }
        for (int i = t; i < 32 * 32; i += 256) {
            int n = i >> 5, k = i & 31;
            W3T[i] = f2bf(w_e2[k * kF + n]);
        }
        for (int i = t; i < 16 * 32; i += 256) {
            int n = i >> 5, k = i & 31;
            float a = 0.f;
            if (n < kH) for (int o = 0; o < kF; o++) a += w_e2[k * kF + o] * w_att[o * kH + n];
            W24T[i] = f2bf(a);
        }
        if (t < kH) {
            float a = b_att[t];
            for (int o = 0; o < kF; o++) a += b_e2[o] * w_att[o * kH + t];
            b24[t] = a;
        }
    }
}

// ---------------------------------------------------------------------------
// K1: MFMA edge kernel (r8-proven). GEMM1->rbf->GEMM2->silu->GEMM3/4.
// ---------------------------------------------------------------------------
__global__ __launch_bounds__(256) void edge_kernel(
    const float* __restrict__ h, const float* __restrict__ x,
    const int* __restrict__ pl, int E_,
    const float* __restrict__ b_in, const float* __restrict__ b_e1,
    const float* __restrict__ b_e2,
    const u16* __restrict__ W1T, const u16* __restrict__ W2T,
    const u16* __restrict__ W3T, const u16* __restrict__ W24T,
    const float* __restrict__ b24,
    float* __restrict__ he_g, float* __restrict__ logit_g,
    float* __restrict__ dir_g, int* __restrict__ counts)
{
    __shared__ __align__(16) u16 s_A[kEM][kAStr];
    __shared__ __align__(16) u16 s_t1[kEM][kBStr];
    __shared__ float s_d[kEM];

    int t = threadIdx.x;
    int T0 = blockIdx.x * kEM;
    int w = t >> 6, lane = t & 63, quad = lane >> 4, l15 = lane & 15;

    {
        int e = t >> 1, half = t & 1;
        int ge = T0 + e;
        bool val = ge < E_;
        int i = 0, j = 0;
        if (val) { i = pl[ge]; j = pl[E_ + ge]; }
        const float4* pi = (const float4*)(h + (size_t)i * kF) + half * 4;
        const float4* pj = (const float4*)(h + (size_t)j * kF) + half * 4;
#pragma unroll
        for (int q = 0; q < 4; q++) {
            float4 a = val ? pi[q] : make_float4(0.f, 0.f, 0.f, 0.f);
            float4 b = val ? pj[q] : make_float4(0.f, 0.f, 0.f, 0.f);
            unsigned* di = (unsigned*)&s_A[e][half * 16 + 4 * q];
            di[0] = pk2(a.x, a.y); di[1] = pk2(a.z, a.w);
            unsigned* dj = (unsigned*)&s_A[e][kF + half * 16 + 4 * q];
            dj[0] = pk2(b.x, b.y); dj[1] = pk2(b.z, b.w);
        }
        if (half == 0) {
            float d = 0.f;
            if (val) {
                float r0 = x[j * 3 + 0] - x[i * 3 + 0];
                float r1 = x[j * 3 + 1] - x[i * 3 + 1];
                float r2 = x[j * 3 + 2] - x[i * 3 + 2];
                d = sqrtf(r0 * r0 + r1 * r1 + r2 * r2);
                float inv = 1.0f / (d + kEps);
                dir_g[(size_t)ge * 3 + 0] = r0 * inv;
                dir_g[(size_t)ge * 3 + 1] = r1 * inv;
                dir_g[(size_t)ge * 3 + 2] = r2 * inv;
                atomicAdd(&counts[i], 1);
            }
            s_d[e] = d;
            s_A[e][114] = f2bf(d);
            s_A[e][115] = 0;
            unsigned* z = (unsigned*)&s_A[e][116];
#pragma unroll
            for (int q = 0; q < 6; q++) z[q] = 0u;
        }
    }
    __syncthreads();

    const float invw = 49.0f / kCut;

    {   // GEMM1: h_cat @ w_in -> rbf -> filt
        bf16x8 a1[2][2];
#pragma unroll
        for (int rt = 0; rt < 2; rt++)
#pragma unroll
            for (int kt = 0; kt < 2; kt++)
                a1[rt][kt] = *(const bf16x8*)&s_A[32 * w + 16 * rt + l15][kt * 32 + quad * 8];
#pragma unroll
        for (int ct = 0; ct < 4; ct++) {
            int c = ct * 16 + l15;
            bf16x8 b0 = *(const bf16x8*)(W1T + (size_t)c * 64 + quad * 8);
            bf16x8 b1 = *(const bf16x8*)(W1T + (size_t)c * 64 + 32 + quad * 8);
            float bin = (c < kRBF) ? b_in[c] : 0.f;
#pragma unroll
            for (int rt = 0; rt < 2; rt++) {
                f32x4 acc = {0.f, 0.f, 0.f, 0.f};
                acc = __builtin_amdgcn_mfma_f32_16x16x32_bf16(a1[rt][0], b0, acc, 0, 0, 0);
                acc = __builtin_amdgcn_mfma_f32_16x16x32_bf16(a1[rt][1], b1, acc, 0, 0, 0);
                if (c < kRBF) {
#pragma unroll
                    for (int r = 0; r < 4; r++) {
                        int row = 32 * w + 16 * rt + quad * 4 + r;
                        float arg = s_d[row] * invw - (float)c;
                        float filt = __expf(-0.5f * arg * arg) * (acc[r] + bin);
                        s_A[row][64 + c] = f2bf(filt);
                    }
                }
            }
        }
    }

    {   // GEMM2: edge_in @ w_e1 -> silu -> t1
        bf16x8 a2[2][4];
#pragma unroll
        for (int rt = 0; rt < 2; rt++)
#pragma unroll
            for (int kt = 0; kt < 4; kt++)
                a2[rt][kt] = *(const bf16x8*)&s_A[32 * w + 16 * rt + l15][kt * 32 + quad * 8];
#pragma unroll
        for (int ct = 0; ct < 2; ct++) {
            int c = ct * 16 + l15;
            bf16x8 bb[4];
#pragma unroll
            for (int kt = 0; kt < 4; kt++)
                bb[kt] = *(const bf16x8*)(W2T + (size_t)c * 128 + kt * 32 + quad * 8);
            float be = b_e1[c];
#pragma unroll
            for (int rt = 0; rt < 2; rt++) {
                f32x4 acc = {0.f, 0.f, 0.f, 0.f};
#pragma unroll
                for (int kt = 0; kt < 4; kt++)
                    acc = __builtin_amdgcn_mfma_f32_16x16x32_bf16(a2[rt][kt], bb[kt], acc, 0, 0, 0);
#pragma unroll
                for (int r = 0; r < 4; r++) {
                    int row = 32 * w + 16 * rt + quad * 4 + r;
                    s_t1[row][c] = f2bf(silu_f(acc[r] + be));
                }
            }
        }
    }

    {   // GEMM3 (he) + GEMM4 (logits)
        bf16x8 a3[2];
#pragma unroll
        for (int rt = 0; rt < 2; rt++)
            a3[rt] = *(const bf16x8*)&s_t1[32 * w + 16 * rt + l15][quad * 8];

#pragma unroll
        for (int ct = 0; ct < 2; ct++) {
            int c = ct * 16 + l15;
            bf16x8 b3 = *(const bf16x8*)(W3T + (size_t)c * 32 + quad * 8);
            float be = b_e2[c];
#pragma unroll
            for (int rt = 0; rt < 2; rt++) {
                f32x4 acc = {0.f, 0.f, 0.f, 0.f};
                acc = __builtin_amdgcn_mfma_f32_16x16x32_bf16(a3[rt], b3, acc, 0, 0, 0);
#pragma unroll
                for (int r = 0; r < 4; r++) {
                    int row = 32 * w + 16 * rt + quad * 4 + r;
                    int ge = T0 + row;
                    if (ge < E_) he_g[(size_t)ge * kF + c] = acc[r] + be;
                }
            }
        }
        {
            bf16x8 b4 = *(const bf16x8*)(W24T + (size_t)l15 * 32 + quad * 8);
            float bb = (l15 < kH) ? b24[l15] : 0.f;
#pragma unroll
            for (int rt = 0; rt < 2; rt++) {
                f32x4 acc = {0.f, 0.f, 0.f, 0.f};
                acc = __builtin_amdgcn_mfma_f32_16x16x32_bf16(a3[rt], b4, acc, 0, 0, 0);
                if (l15 < kH) {
#pragma unroll
                    for (int r = 0; r < 4; r++) {
                        int row = 32 * w + 16 * rt + quad * 4 + r;
                        int ge = T0 + row;
                        if (ge < E_) {
                            float a = acc[r] + bb;
                            a = (a >= 0.f) ? a : 2.f * (__expf(0.5f * a) - 1.f);
                            float dd = s_d[row];
                            float cut = (dd < kCut)
                                ? 0.5f * (__cosf(0.62831853071795864f * dd) + 1.f) : 0.f;
                            logit_g[(size_t)ge * kH + l15] = a * cut;
                        }
                    }
                }
            }
        }
    }
}

// ---------------------------------------------------------------------------
// K2: exclusive scan, barrier-light
// ---------------------------------------------------------------------------
__global__ __launch_bounds__(1024) void scan_kernel(
    const int* __restrict__ counts, int* __restrict__ offsets, int n)
{
    __shared__ int buf[1024];
    int t = threadIdx.x;
    int chunk = (n + 1023) >> 10;
    int lo = t * chunk;
    int s = 0;
    for (int i = 0; i < chunk; i++) {
        int g = lo + i;
        if (g < n) s += counts[g];
    }
    buf[t] = s;
    __syncthreads();
    for (int off = 1; off < 1024; off <<= 1) {
        int v = (t >= off) ? buf[t - off] : 0;
        __syncthreads();
        buf[t] += v;
        __syncthreads();
    }
    int run = buf[t] - s;
    for (int i = 0; i < chunk; i++) {
        int g = lo + i;
        if (g < n) { offsets[g] = run; run += counts[g]; }
    }
    if (t == 1023) offsets[n] = buf[1023];
}

// ---------------------------------------------------------------------------
// K3: scatter edges into CSR order
// ---------------------------------------------------------------------------
__global__ __launch_bounds__(256) void scatter_kernel(
    const int* __restrict__ pl, const int* __restrict__ offsets,
    int* __restrict__ cursor, int* __restrict__ sorted, int E_)
{
    int e = blockIdx.x * 256 + threadIdx.x;
    if (e < E_) {
        int i = pl[e];
        int p = atomicAdd(&cursor[i], 1);
        sorted[offsets[i] + p] = e;
    }
}

// ---------------------------------------------------------------------------
// K4: per-node softmax stats (wave per node)
// ---------------------------------------------------------------------------
__global__ __launch_bounds__(256) void stats_kernel(
    const float* __restrict__ logit_g, const int* __restrict__ offsets,
    const int* __restrict__ sorted,
    float* __restrict__ m_g, float* __restrict__ invs_g, int N_)
{
    int wave = threadIdx.x >> 6;
    int lane = threadIdx.x & 63;
    int node = blockIdx.x * 4 + wave;
    if (node >= N_) return;
    int base = offsets[node];
    int deg  = offsets[node + 1] - base;

    float m[kH], ss[kH];
#pragma unroll
    for (int hh = 0; hh < kH; hh++) { m[hh] = -1e30f; ss[hh] = 0.f; }
    for (int e = lane; e < deg; e += 64) {
        int ed = sorted[base + e];
        const float* lp = logit_g + (size_t)ed * kH;
#pragma unroll
        for (int hh = 0; hh < kH; hh++) {
            float vv = lp[hh];
            if (vv > m[hh]) { ss[hh] *= __expf(m[hh] - vv); m[hh] = vv; }
            ss[hh] += __expf(vv - m[hh]);
        }
    }
#pragma unroll
    for (int hh = 0; hh < kH; hh++) {
        float mm = m[hh], s2 = ss[hh];
#pragma unroll
        for (int off = 32; off >= 1; off >>= 1) {
            float mo = __shfl_xor(mm, off);
            float so = __shfl_xor(s2, off);
            float mn = fmaxf(mm, mo);
            s2 = s2 * __expf(mm - mn) + so * __expf(mo - mn);
            mm = mn;
        }
        if (lane == 0) {
            m_g[(size_t)node * kH + hh] = mm;
            invs_g[(size_t)node * kH + hh] = (s2 > 0.f) ? 1.f / s2 : 0.f;
        }
    }
}

// ---------------------------------------------------------------------------
// K5: MFMA xmix + windowed in-tile reductions. Each wave owns a 32-edge
// window; each lane owns 4 consecutive columns (b64 reads, float4 flushes).
// Complete runs -> nodeacc; window-boundary runs -> bpart (2 slots/window).
// ---------------------------------------------------------------------------
__global__ __launch_bounds__(256) void xmix_kernel(
    const float* __restrict__ he_g, const float* __restrict__ logit_g,
    const float* __restrict__ dir_g,
    const int* __restrict__ pl, const int* __restrict__ sorted,
    const float* __restrict__ m_g, const float* __restrict__ invs_g,
    const u16* __restrict__ wxT, int E_,
    float* __restrict__ nodeacc, float* __restrict__ bpart, int* __restrict__ bid)
{
    __shared__ __align__(16) u16 s_buf[kM][kStr];   // sem, then T
    __shared__ float s_att[kM][kH];
    __shared__ __align__(16) float s_dir4[kM][4];
    __shared__ int   s_ed[kM];
    __shared__ int   s_node[kM];
    __shared__ int   s_prev, s_next;

    int t = threadIdx.x;
    int T0 = blockIdx.x * kM;
    int cp = min(kM, E_ - T0);

    if (t < kM) {
        int gi = T0 + t;
        int ed = (gi < E_) ? sorted[gi] : -1;
        s_ed[t] = ed;
        s_node[t] = (ed >= 0) ? pl[ed] : -1;
    }
    if (t == 0) {
        s_prev = (T0 > 0) ? pl[sorted[T0 - 1]] : -2;
        s_next = (T0 + cp < E_) ? pl[sorted[T0 + cp]] : -2;
    }
    __syncthreads();

    int w    = t >> 6;
    int lane = t & 63;
    int quad = lane >> 4;
    int l15  = lane & 15;

    // ---- per-wave window params ----
    int ws = 32 * w;
    int we = min(ws + 32, cp);
    bool winvalid = (ws < cp);
    bool contL = false, contR = false;
    if (winvalid) {
        int nfirst = s_node[ws], nlast = s_node[we - 1];
        contL = (w == 0) ? (s_prev == nfirst) : (s_node[ws - 1] == nfirst);
        contR = (we == cp) ? (s_next == nlast) : (s_node[we] == nlast);
    }
    if (lane == 0) {
        int b0 = -1, b1 = -1;
        if (winvalid) {
            int nfirst = s_node[ws], nlast = s_node[we - 1];
            b0 = contL ? nfirst : -1;
            if (contR && !(nfirst == nlast && contL)) b1 = nlast;
        }
        bid[8 * blockIdx.x + 2 * w + 0] = b0;
        bid[8 * blockIdx.x + 2 * w + 1] = b1;
    }
    bool active_w = winvalid && (lane < 56);
    int c0 = 4 * lane;   // columns c0..c0+3 (lane<56)

    for (int idx = t; idx < kM * kH; idx += 256) {
        int e = idx / kH, hh = idx - e * kH;
        int ed = s_ed[e];
        float a = 0.f;
        if (ed >= 0) {
            int nd = s_node[e];
            a = __expf(logit_g[(size_t)ed * kH + hh] - m_g[(size_t)nd * kH + hh])
                * invs_g[(size_t)nd * kH + hh];
        }
        s_att[e][hh] = a;
    }
    for (int idx = t; idx < cp * 3; idx += 256) {
        int e = idx / 3, xx = idx - e * 3;
        s_dir4[e][xx] = dir_g[(size_t)s_ed[e] * 3 + xx];
    }
    __syncthreads();

    // sem build (bf16)
#pragma unroll
    for (int p = 0; p < kM * kF / 256; p++) {
        int idx = t + 256 * p;
        int e = idx >> 5, f = idx & 31;
        int ed = s_ed[e];
        float hv = (ed >= 0) ? he_g[(size_t)ed * kF + f] : 0.f;
        u16 sw[7];
#pragma unroll
        for (int hh = 0; hh < kH; hh++) sw[hh] = f2bf(hv * s_att[e][hh]);
        u16* dst = &s_buf[e][f * 7];
        if ((f & 1) == 0) {
            *(unsigned int*)(dst)     = (unsigned int)sw[0] | ((unsigned int)sw[1] << 16);
            *(unsigned int*)(dst + 2) = (unsigned int)sw[2] | ((unsigned int)sw[3] << 16);
            *(unsigned int*)(dst + 4) = (unsigned int)sw[4] | ((unsigned int)sw[5] << 16);
            dst[6] = sw[6];
        } else {
            dst[0] = sw[0];
            *(unsigned int*)(dst + 1) = (unsigned int)sw[1] | ((unsigned int)sw[2] << 16);
            *(unsigned int*)(dst + 3) = (unsigned int)sw[3] | ((unsigned int)sw[4] << 16);
            *(unsigned int*)(dst + 5) = (unsigned int)sw[5] | ((unsigned int)sw[6] << 16);
        }
    }
    __syncthreads();

    // hisem walk (windowed, b64 column reads, float4 flush)
    if (active_w) {
        float hs0 = 0.f, hs1 = 0.f, hs2 = 0.f, hs3 = 0.f;
        int rs = ws;
        for (int e = ws; e < we; e++) {
            if (s_node[e] != s_node[rs]) {
                bool comp = (rs > ws) || !contL;
                float4 vv = make_float4(hs0, hs1, hs2, hs3);
                if (comp) *(float4*)&nodeacc[(size_t)s_node[rs] * 896 + 672 + c0] = vv;
                else *(float4*)&bpart[(size_t)(8 * blockIdx.x + 2 * w) * 896 + 672 + c0] = vv;
                hs0 = hs1 = hs2 = hs3 = 0.f; rs = e;
            }
            uint2 pv = *(const uint2*)&s_buf[e][c0];
            hs0 += bf2f((u16)pv.x); hs1 += bf2f((u16)(pv.x >> 16));
            hs2 += bf2f((u16)pv.y); hs3 += bf2f((u16)(pv.y >> 16));
        }
        bool t0 = (rs == ws);
        bool comp = ((!t0) || !contL) && !contR;
        float4 vv = make_float4(hs0, hs1, hs2, hs3);
        if (comp) *(float4*)&nodeacc[(size_t)s_node[rs] * 896 + 672 + c0] = vv;
        else {
            int slot = (t0 && contL) ? 0 : 1;
            *(float4*)&bpart[(size_t)(8 * blockIdx.x + 2 * w + slot) * 896 + 672 + c0] = vv;
        }
    }

    // MFMA fragments
    bf16x8 afr[2][7];
#pragma unroll
    for (int rt = 0; rt < 2; rt++)
#pragma unroll
        for (int kt = 0; kt < 7; kt++)
            afr[rt][kt] = *(const bf16x8*)&s_buf[32 * w + 16 * rt + l15][kt * 32 + quad * 8];

    bf16x8 bA[7], bB[7];
    {
        const u16* bp = wxT + (size_t)l15 * kC + quad * 8;
#pragma unroll
        for (int kt = 0; kt < 7; kt++) bA[kt] = *(const bf16x8*)(bp + kt * 32);
    }
    __syncthreads();   // hisem walk + A-loads done before T write-back

    for (int ct = 0; ct < 14; ct++) {
        bf16x8* cur = (ct & 1) ? bB : bA;
        bf16x8* nxt = (ct & 1) ? bA : bB;
        if (ct < 13) {
            const u16* bp = wxT + (size_t)((ct + 1) * 16 + l15) * kC + quad * 8;
#pragma unroll
            for (int kt = 0; kt < 7; kt++) nxt[kt] = *(const bf16x8*)(bp + kt * 32);
        }
        f32x4 acc0 = {0.f, 0.f, 0.f, 0.f};
        f32x4 acc1 = {0.f, 0.f, 0.f, 0.f};
#pragma unroll
        for (int kt = 0; kt < 7; kt++) {
            acc0 = __builtin_amdgcn_mfma_f32_16x16x32_bf16(afr[0][kt], cur[kt], acc0, 0, 0, 0);
            acc1 = __builtin_amdgcn_mfma_f32_16x16x32_bf16(afr[1][kt], cur[kt], acc1, 0, 0, 0);
        }
        int colg = ct * 16 + l15;
#pragma unroll
        for (int s = 0; s < 2; s++) {
            f32x4 ac = s ? acc1 : acc0;
            int rbase = 32 * w + 16 * s + quad * 4;
#pragma unroll
            for (int r = 0; r < 4; r++)
                s_buf[rbase + r][colg] = f2bf(tanh_f(ac[r]));
        }
    }
    __syncthreads();

    // comb walk (windowed, b64 T reads, broadcast dir b128, float4 flushes)
    if (active_w) {
        float a0[4] = {0.f, 0.f, 0.f, 0.f};
        float a1[4] = {0.f, 0.f, 0.f, 0.f};
        float a2[4] = {0.f, 0.f, 0.f, 0.f};
        int rs = ws;
        for (int e = ws; e < we; e++) {
            if (s_node[e] != s_node[rs]) {
                bool comp = (rs > ws) || !contL;
                float* p = comp ? (nodeacc + (size_t)s_node[rs] * 896)
                                : (bpart + (size_t)(8 * blockIdx.x + 2 * w) * 896);
                *(float4*)&p[c0]       = make_float4(a0[0], a0[1], a0[2], a0[3]);
                *(float4*)&p[224 + c0] = make_float4(a1[0], a1[1], a1[2], a1[3]);
                *(float4*)&p[448 + c0] = make_float4(a2[0], a2[1], a2[2], a2[3]);
#pragma unroll
                for (int q = 0; q < 4; q++) { a0[q] = 0.f; a1[q] = 0.f; a2[q] = 0.f; }
                rs = e;
            }
            float4 dd = *(const float4*)&s_dir4[e][0];
            uint2 pv = *(const uint2*)&s_buf[e][c0];
            float Tv[4];
            Tv[0] = bf2f((u16)pv.x); Tv[1] = bf2f((u16)(pv.x >> 16));
            Tv[2] = bf2f((u16)pv.y); Tv[3] = bf2f((u16)(pv.y >> 16));
#pragma unroll
            for (int q = 0; q < 4; q++) {
                a0[q] += Tv[q] * dd.x;
                a1[q] += Tv[q] * dd.y;
                a2[q] += Tv[q] * dd.z;
            }
        }
        bool t0 = (rs == ws);
        bool comp = ((!t0) || !contL) && !contR;
        float* p;
        if (comp) p = nodeacc + (size_t)s_node[rs] * 896;
        else {
            int slot = (t0 && contL) ? 0 : 1;
            p = bpart + (size_t)(8 * blockIdx.x + 2 * w + slot) * 896;
        }
        *(float4*)&p[c0]       = make_float4(a0[0], a0[1], a0[2], a0[3]);
        *(float4*)&p[224 + c0] = make_float4(a1[0], a1[1], a1[2], a1[3]);
        *(float4*)&p[448 + c0] = make_float4(a2[0], a2[1], a2[2], a2[3]);
    }
}

// ---------------------------------------------------------------------------
// K6: node epilogue. 4 nodes/block; gather nodeacc/bpart (32-edge windows);
// MLPs with weight-value reuse across the 4 nodes.
// ---------------------------------------------------------------------------
__global__ __launch_bounds__(256) void node_kernel(
    const float* __restrict__ h, const float* __restrict__ x, const float* __restrict__ v,
    const float* __restrict__ nodeacc, const float* __restrict__ bpart,
    const int* __restrict__ bid, const int* __restrict__ offs,
    const float* __restrict__ w_n1, const float* __restrict__ b_n1,
    const float* __restrict__ w_n2, const float* __restrict__ b_n2,
    const float* __restrict__ w_pn1, const float* __restrict__ b_pn1,
    const float* __restrict__ w_pn2, const float* __restrict__ b_pn2,
    const float* __restrict__ w_v1, const float* __restrict__ b_v1,
    const float* __restrict__ w_v2, const float* __restrict__ w_vmix,
    float* __restrict__ out_h, float* __restrict__ out_x, float* __restrict__ out_v,
    int N_)
{
    __shared__ float s_cm[4][3][kC];
    __shared__ float s_cnsq[4][kC];
    __shared__ float s_ni[4][288];          // [h | hisem | spat]
    __shared__ float s_part[8][4][kF];
    __shared__ float s_hn[4][kF], s_sp1[4][kF], s_spat[4][kF], s_n1v[4][kF], s_g1[4][kF];
    __shared__ float s_pdv[4][3][8];
    __shared__ float s_gate[4], s_dv[4][3];

    int t = threadIdx.x;
    int n0 = blockIdx.x * 4;

    if (t < kC) {
        for (int nd = 0; nd < 4; nd++) {
            int node = n0 + nd;
            if (node >= N_) break;
            int base = offs[node], end = offs[node + 1];
            int deg = end - base;
            float a0 = 0.f, a1 = 0.f, a2 = 0.f, hh = 0.f;
            if (deg > 0) {
                int wlo = base >> 5, whi = (end - 1) >> 5;
                if (wlo == whi) {
                    const float* p = nodeacc + (size_t)node * 896;
                    a0 = p[t]; a1 = p[224 + t]; a2 = p[448 + t]; hh = p[672 + t];
                } else {
                    for (int W = wlo; W <= whi; W++) {
#pragma unroll
                        for (int s = 0; s < 2; s++) {
                            if (bid[2 * W + s] == node) {
                                const float* p = bpart + (size_t)(2 * W + s) * 896;
                                a0 += p[t]; a1 += p[224 + t]; a2 += p[448 + t]; hh += p[672 + t];
                            }
                        }
                    }
                }
            }
            float invc = 1.f / fmaxf((float)deg, 1.f);
            float m0 = a0 * invc, m1 = a1 * invc, m2 = a2 * invc;
            s_cm[nd][0][t] = m0; s_cm[nd][1][t] = m1; s_cm[nd][2][t] = m2;
            s_cnsq[nd][t] = m0 * m0 + m1 * m1 + m2 * m2;
            s_ni[nd][kF + t] = hh;
        }
    } else {
        int ln = t - 224;   // 0..31
        for (int nd = 0; nd < 4; nd++) {
            int node = n0 + nd;
            float hv = (node < N_) ? h[(size_t)node * kF + ln] : 0.f;
            s_hn[nd][ln] = hv;
            s_ni[nd][ln] = hv;
        }
    }
    __syncthreads();

    int o = t & 31, g = t >> 5;
    {   // pn1 partials, 4 nodes per weight load
        float acc[4] = {0.f, 0.f, 0.f, 0.f};
        int cb = g * 28;
        for (int i = 0; i < 28; i++) {
            float wv = w_pn1[(cb + i) * kF + o];
#pragma unroll
            for (int nd = 0; nd < 4; nd++) acc[nd] += s_cnsq[nd][cb + i] * wv;
        }
#pragma unroll
        for (int nd = 0; nd < 4; nd++) s_part[g][nd][o] = acc[nd];
    }
    __syncthreads();
    if (t < 128) {
        int nd = t >> 5;
        float a = b_pn1[o];
#pragma unroll
        for (int g2 = 0; g2 < 8; g2++) a += s_part[g2][nd][o];
        s_sp1[nd][o] = silu_f(a);
    } else {
        int nd = (t - 128) >> 5;
        float a = b_v1[o];
        for (int f = 0; f < kF; f++) a += s_hn[nd][f] * w_v1[f * kF + o];
        s_g1[nd][o] = silu_f(a);
    }
    __syncthreads();
    if (t < 128) {
        int nd = t >> 5;
        float a = b_pn2[o];
        for (int o2 = 0; o2 < kF; o2++) a += s_sp1[nd][o2] * w_pn2[o2 * kF + o];
        s_spat[nd][o] = silu_f(a);
    } else if (t < 132) {
        int nd = t - 128;
        float a = 0.f;
        for (int o2 = 0; o2 < kF; o2++) a += s_g1[nd][o2] * w_v2[o2];
        s_gate[nd] = 2.f / (1.f + __expf(-a));
    } else if (t >= 160) {   // 96 threads: dv partials
        int q = t - 160; int nd = q / 24; int r = q - nd * 24;
        int xx = r >> 3, ln = r & 7;
        float a = 0.f;
        for (int c = ln; c < kC; c += 8) a += w_vmix[c] * s_cm[nd][xx][c];
        s_pdv[nd][xx][ln] = a;
    }
    __syncthreads();
    if (t < 128) {
        int nd = t >> 5;
        s_ni[nd][kF + kC + o] = s_spat[nd][o];
    } else if (t < 140) {
        int q = t - 128; int nd = q / 3; int xx = q - nd * 3;
        float a = 0.f;
#pragma unroll
        for (int ln = 0; ln < 8; ln++) a += s_pdv[nd][xx][ln];
        s_dv[nd][xx] = a;
    }
    __syncthreads();
    {   // n1 partials: 8 groups x 36 rows
        float acc[4] = {0.f, 0.f, 0.f, 0.f};
        int rb = g * 36;
        for (int i = 0; i < 36; i++) {
            float wv = w_n1[(rb + i) * kF + o];
#pragma unroll
            for (int nd = 0; nd < 4; nd++) acc[nd] += s_ni[nd][rb + i] * wv;
        }
#pragma unroll
        for (int nd = 0; nd < 4; nd++) s_part[g][nd][o] = acc[nd];
    }
    __syncthreads();
    if (t < 128) {
        int nd = t >> 5;
        float a = b_n1[o];
#pragma unroll
        for (int g2 = 0; g2 < 8; g2++) a += s_part[g2][nd][o];
        s_n1v[nd][o] = silu_f(a);
    }
    __syncthreads();
    if (t < 128) {
        int nd = t >> 5; int node = n0 + nd;
        if (node < N_) {
            float a = b_n2[o];
            for (int o2 = 0; o2 < kF; o2++) a += s_n1v[nd][o2] * w_n2[o2 * kF + o];
            out_h[(size_t)node * kF + o] = s_hn[nd][o] + silu_f(a);
        }
    } else if (t < 140) {
        int q = t - 128; int nd = q / 3; int xx = q - nd * 3;
        int node = n0 + nd;
        if (node < N_) {
            float vv = v[(size_t)node * 3 + xx];
            float vu = s_gate[nd] * vv + s_dv[nd][xx];
            out_v[(size_t)node * 3 + xx] = vu;
            out_x[(size_t)node * 3 + xx] = x[(size_t)node * 3 + xx] + vu;
        }
    }
}

// ---------------------------------------------------------------------------
extern "C" void kernel_launch(void* const* d_in, const int* in_sizes, int n_in,
                              void* d_out, int out_size, void* d_ws, size_t ws_size,
                              hipStream_t stream)
{
    const float* h      = (const float*)d_in[0];
    const float* x      = (const float*)d_in[1];
    const float* v      = (const float*)d_in[2];
    const int*   pl     = (const int*)d_in[3];
    const float* w_in   = (const float*)d_in[4];
    const float* b_in   = (const float*)d_in[5];
    const float* w_e1   = (const float*)d_in[6];
    const float* b_e1   = (const float*)d_in[7];
    const float* w_e2   = (const float*)d_in[8];
    const float* b_e2   = (const float*)d_in[9];
    const float* w_att  = (const float*)d_in[10];
    const float* b_att  = (const float*)d_in[11];
    const float* w_n1   = (const float*)d_in[12];
    const float* b_n1   = (const float*)d_in[13];
    const float* w_n2   = (const float*)d_in[14];
    const float* b_n2   = (const float*)d_in[15];
    const float* w_pn1  = (const float*)d_in[16];
    const float* b_pn1  = (const float*)d_in[17];
    const float* w_pn2  = (const float*)d_in[18];
    const float* b_pn2  = (const float*)d_in[19];
    const float* w_v1   = (const float*)d_in[20];
    const float* b_v1   = (const float*)d_in[21];
    const float* w_v2   = (const float*)d_in[22];
    const float* w_xmix = (const float*)d_in[23];
    const float* w_vmix = (const float*)d_in[24];

    const int E_ = in_sizes[3] / 2;
    const int N_ = in_sizes[0] / kF;
    const int nblk = (E_ + kM - 1) / kM;

    // Workspace (~116 MB; 16B-aligned segments first)
    char* w = (char*)d_ws;
    u16*   wxT     = (u16*)w;   w += (size_t)kC * kC * 2;
    u16*   W1T     = (u16*)w;   w += (size_t)64 * 64 * 2;
    u16*   W2T     = (u16*)w;   w += (size_t)32 * 128 * 2;
    u16*   W3T     = (u16*)w;   w += (size_t)32 * 32 * 2;
    u16*   W24T    = (u16*)w;   w += (size_t)16 * 32 * 2;
    float* b24     = (float*)w; w += 8 * 4;
    float* he_g    = (float*)w; w += (size_t)E_ * kF * 4;
    float* logit_g = (float*)w; w += (size_t)E_ * kH * 4;
    float* dir_g   = (float*)w; w += (size_t)E_ * 3 * 4;
    float* m_g     = (float*)w; w += (size_t)N_ * kH * 4;
    float* invs_g  = (float*)w; w += (size_t)N_ * kH * 4;
    float* nodeacc = (float*)w; w += (size_t)N_ * 896 * 4;       // [N][4][224]
    float* bpart   = (float*)w; w += (size_t)8 * nblk * 896 * 4; // [8*nblk][4][224]
    int*   bid     = (int*)w;   w += (size_t)8 * nblk * 4;
    int* counts    = (int*)w;   w += (size_t)N_ * 4;
    int* offs      = (int*)w;   w += (size_t)(N_ + 1) * 4;
    int* cursor    = (int*)w;   w += (size_t)N_ * 4;
    int* sorted    = (int*)w;   w += (size_t)E_ * 4;

    float* out_h = (float*)d_out;
    float* out_x = out_h + (size_t)N_ * kF;
    float* out_v = out_x + (size_t)N_ * 3;

    init_kernel<<<dim3((kC * kC + 255) / 256), dim3(256), 0, stream>>>(
        w_xmix, w_in, w_e1, w_e2, w_att, b_e2, b_att,
        wxT, W1T, W2T, W3T, W24T, b24, counts, cursor, N_);

    edge_kernel<<<dim3((E_ + kEM - 1) / kEM), dim3(256), 0, stream>>>(
        h, x, pl, E_, b_in, b_e1, b_e2, W1T, W2T, W3T, W24T, b24,
        he_g, logit_g, dir_g, counts);

    scan_kernel<<<dim3(1), dim3(1024), 0, stream>>>(counts, offs, N_);

    scatter_kernel<<<dim3((E_ + 255) / 256), dim3(256), 0, stream>>>(
        pl, offs, cursor, sorted, E_);

    stats_kernel<<<dim3((N_ + 3) / 4), dim3(256), 0, stream>>>(
        logit_g, offs, sorted, m_g, invs_g, N_);

    xmix_kernel<<<dim3(nblk), dim3(256), 0, stream>>>(
        he_g, logit_g, dir_g, pl, sorted, m_g, invs_g, wxT, E_,
        nodeacc, bpart, bid);

    node_kernel<<<dim3((N_ + 3) / 4), dim3(256), 0, stream>>>(
        h, x, v, nodeacc, bpart, bid, offs,
        w_n1, b_n1, w_n2, b_n2, w_pn1, b_pn1, w_pn2, b_pn2,
        w_v1, b_v1, w_v2, w_vmix, out_h, out_x, out_v, N_);
}